// Round 2
// baseline (4034.189 us; speedup 1.0000x reference)
//
#include <hip/hip_runtime.h>

#define N_NODES 50000
#define N_EDGES 800000
#define EP (N_EDGES + N_NODES)   /* 850000 edges incl. self loops */
#define HEADS 8
#define NEG 0.2f

// ---- helpers -------------------------------------------------------------

// order-preserving float->uint encoding for atomicMax on floats
__device__ __forceinline__ unsigned fenc(float f) {
    unsigned u = __float_as_uint(f);
    return (u & 0x80000000u) ? ~u : (u | 0x80000000u);
}
__device__ __forceinline__ float fdec(unsigned e) {
    unsigned u = (e & 0x80000000u) ? (e & 0x7FFFFFFFu) : ~e;
    return __uint_as_float(u);
}
#define ENC_NEG_INF 0x007FFFFFu   /* fenc(-inf) */

__device__ __forceinline__ void get_edge(const int* __restrict__ ei, int e, int& s, int& d) {
    if (e < N_EDGES) { s = ei[e]; d = ei[N_EDGES + e]; }
    else             { s = d = e - N_EDGES; }           // self loop
}

__device__ __forceinline__ float lrelu(float v) { return v > 0.f ? v : NEG * v; }

// ---- GEMM: out[M,NC] = A[M,K] @ W[K,NC], 8 rows per block ---------------

template<int K, int NC>
__global__ __launch_bounds__(NC) void gemm_rows(const float* __restrict__ A,
                                                const float* __restrict__ W,
                                                float* __restrict__ out) {
    constexpr int ROWS = 8;
    __shared__ float a_lds[ROWS * K];
    const int row0 = blockIdx.x * ROWS;
    const int tid  = threadIdx.x;

    const float* Ap = A + (size_t)row0 * K;
    for (int i = tid; i < ROWS * K; i += NC) a_lds[i] = Ap[i];
    __syncthreads();

    float acc[ROWS];
#pragma unroll
    for (int r = 0; r < ROWS; r++) acc[r] = 0.f;

#pragma unroll 4
    for (int k = 0; k < K; k++) {
        float w = W[k * NC + tid];
#pragma unroll
        for (int r = 0; r < ROWS; r++) acc[r] = fmaf(a_lds[r * K + k], w, acc[r]);
    }
    float* o = out + (size_t)row0 * NC + tid;
#pragma unroll
    for (int r = 0; r < ROWS; r++) o[(size_t)r * NC] = acc[r];
}

// ---- per-(node,head) attention coefficients + state init ----------------

template<int C>
__global__ void att_init(const float* __restrict__ h,
                         const float* __restrict__ att_s,
                         const float* __restrict__ att_d,
                         float* __restrict__ a_src, float* __restrict__ a_dst,
                         unsigned* __restrict__ m_enc, float* __restrict__ denom) {
    int t = blockIdx.x * blockDim.x + threadIdx.x;
    if (t >= N_NODES * HEADS) return;
    const int hh = t & 7;
    const float* hp = h + (size_t)(t >> 3) * (HEADS * C) + hh * C;
    float ss = 0.f, dd = 0.f;
#pragma unroll
    for (int c = 0; c < C; c++) {
        float v = hp[c];
        ss = fmaf(v, att_s[hh * C + c], ss);
        dd = fmaf(v, att_d[hh * C + c], dd);
    }
    a_src[t] = ss;
    a_dst[t] = dd;
    m_enc[t] = ENC_NEG_INF;
    denom[t] = 0.f;
}

// ---- edge pass 1: segment max via atomicMax on encoded floats -----------

__global__ void edge_max(const int* __restrict__ ei, const float* __restrict__ a_src,
                         const float* __restrict__ a_dst, unsigned* __restrict__ m_enc) {
    int t = blockIdx.x * blockDim.x + threadIdx.x;
    if (t >= EP * HEADS) return;
    int e = t >> 3, hh = t & 7;
    int s, d; get_edge(ei, e, s, d);
    float v = lrelu(a_src[s * HEADS + hh] + a_dst[d * HEADS + hh]);
    atomicMax(&m_enc[d * HEADS + hh], fenc(v));
}

// ---- edge pass 2: softmax denominator -----------------------------------

__global__ void edge_denom(const int* __restrict__ ei, const float* __restrict__ a_src,
                           const float* __restrict__ a_dst, const unsigned* __restrict__ m_enc,
                           float* __restrict__ denom) {
    int t = blockIdx.x * blockDim.x + threadIdx.x;
    if (t >= EP * HEADS) return;
    int e = t >> 3, hh = t & 7;
    int s, d; get_edge(ei, e, s, d);
    int idx = d * HEADS + hh;
    float v = lrelu(a_src[s * HEADS + hh] + a_dst[idx]);
    atomicAdd(&denom[idx], expf(v - fdec(m_enc[idx])));
}

// ---- edge pass 3: weighted gather-scatter (layer 1, C=32, 256 feats) ----
// 4 edges per 256-thread block; lane l handles float4 at feat 4*l; head = l>>3

__global__ __launch_bounds__(256) void scatter_c32(const int* __restrict__ ei,
        const float* __restrict__ hsrc, const float* __restrict__ a_src,
        const float* __restrict__ a_dst, const unsigned* __restrict__ m_enc,
        const float* __restrict__ denom, float* __restrict__ acc) {
    const int lane = threadIdx.x & 63;
    const int e = blockIdx.x * 4 + (threadIdx.x >> 6);
    if (e >= EP) return;
    int s, d; get_edge(ei, e, s, d);
    const int hh  = lane >> 3;
    const int idx = d * HEADS + hh;
    float v = lrelu(a_src[s * HEADS + hh] + a_dst[idx]);
    const float alpha = expf(v - fdec(m_enc[idx])) / (denom[idx] + 1e-16f);
    const float4 hv = *(const float4*)(hsrc + (size_t)s * 256 + lane * 4);
    float* ap = acc + (size_t)d * 256 + lane * 4;
    atomicAdd(ap + 0, hv.x * alpha);
    atomicAdd(ap + 1, hv.y * alpha);
    atomicAdd(ap + 2, hv.z * alpha);
    atomicAdd(ap + 3, hv.w * alpha);
}

// ---- edge pass 3 (layer 2, C=16, 128 feats): lane l -> float2 at 2*l ----

__global__ __launch_bounds__(256) void scatter_c16(const int* __restrict__ ei,
        const float* __restrict__ hsrc, const float* __restrict__ a_src,
        const float* __restrict__ a_dst, const unsigned* __restrict__ m_enc,
        const float* __restrict__ denom, float* __restrict__ acc) {
    const int lane = threadIdx.x & 63;
    const int e = blockIdx.x * 4 + (threadIdx.x >> 6);
    if (e >= EP) return;
    int s, d; get_edge(ei, e, s, d);
    const int hh  = lane >> 3;
    const int idx = d * HEADS + hh;
    float v = lrelu(a_src[s * HEADS + hh] + a_dst[idx]);
    const float alpha = expf(v - fdec(m_enc[idx])) / (denom[idx] + 1e-16f);
    const float2 hv = *(const float2*)(hsrc + (size_t)s * 128 + lane * 2);
    float* ap = acc + (size_t)d * 128 + lane * 2;
    atomicAdd(ap + 0, hv.x * alpha);
    atomicAdd(ap + 1, hv.y * alpha);
}

// ---- epilogues ----------------------------------------------------------

__global__ void elu_bias(float* __restrict__ x, const float* __restrict__ bias) {
    int t = blockIdx.x * blockDim.x + threadIdx.x;
    if (t >= N_NODES * 256) return;
    float v = x[t] + bias[t & 255];
    x[t] = v > 0.f ? v : expf(v) - 1.f;
}

__global__ void head_mean(const float* __restrict__ acc, const float* __restrict__ bias,
                          float* __restrict__ out) {
    int t = blockIdx.x * blockDim.x + threadIdx.x;
    if (t >= N_NODES * 16) return;
    int n = t >> 4, c = t & 15;
    const float* p = acc + (size_t)n * 128 + c;
    float s = 0.f;
#pragma unroll
    for (int h = 0; h < HEADS; h++) s += p[h * 16];
    out[t] = s * 0.125f + bias[c];
}

// ---- host ---------------------------------------------------------------

extern "C" void kernel_launch(void* const* d_in, const int* in_sizes, int n_in,
                              void* d_out, int out_size, void* d_ws, size_t ws_size,
                              hipStream_t stream) {
    const float* x        = (const float*)d_in[0];
    const int*   ei       = (const int*)d_in[1];
    const float* W1       = (const float*)d_in[2];
    const float* att_src1 = (const float*)d_in[3];
    const float* att_dst1 = (const float*)d_in[4];
    const float* bias1    = (const float*)d_in[5];
    const float* W2       = (const float*)d_in[6];
    const float* att_src2 = (const float*)d_in[7];
    const float* att_dst2 = (const float*)d_in[8];
    const float* bias2    = (const float*)d_in[9];
    float* out = (float*)d_out;

    char* ws = (char*)d_ws;
    const size_t SZ_NF  = (size_t)N_NODES * 256 * 4;   // 51.2 MB
    const size_t SZ_NF2 = (size_t)N_NODES * 128 * 4;   // 25.6 MB
    float*    h1    = (float*)(ws);                    // [N,256]
    float*    acc1  = (float*)(ws + SZ_NF);            // [N,256]; becomes x2 (elu) in place
    float*    h2    = (float*)(ws);                    // overlays h1 (dead after scatter_c32)
    float*    acc2  = (float*)(ws + SZ_NF2);           // second half of former h1 region
    char*     aux   = ws + 2 * SZ_NF;                  // 102.4 MB offset
    float*    a_src = (float*)(aux);                   // [N,8] fp32
    float*    a_dst = (float*)(aux + 1600000);
    unsigned* m_enc = (unsigned*)(aux + 3200000);
    float*    denom = (float*)(aux + 4800000);         // total ws use: 108.8 MB

    const int EH_BLOCKS = (EP * HEADS + 255) / 256;
    const int NH_BLOCKS = (N_NODES * HEADS + 255) / 256;

    // ---- layer 1 ----
    hipMemsetAsync(acc1, 0, SZ_NF, stream);
    gemm_rows<256, 256><<<N_NODES / 8, 256, 0, stream>>>(x, W1, h1);
    att_init<32><<<NH_BLOCKS, 256, 0, stream>>>(h1, att_src1, att_dst1, a_src, a_dst, m_enc, denom);
    edge_max<<<EH_BLOCKS, 256, 0, stream>>>(ei, a_src, a_dst, m_enc);
    edge_denom<<<EH_BLOCKS, 256, 0, stream>>>(ei, a_src, a_dst, m_enc, denom);
    scatter_c32<<<EP / 4, 256, 0, stream>>>(ei, h1, a_src, a_dst, m_enc, denom, acc1);
    elu_bias<<<(N_NODES * 256 + 255) / 256, 256, 0, stream>>>(acc1, bias1);

    // ---- layer 2 ----
    hipMemsetAsync(acc2, 0, SZ_NF2, stream);
    gemm_rows<256, 128><<<N_NODES / 8, 128, 0, stream>>>(acc1, W2, h2);
    att_init<16><<<NH_BLOCKS, 256, 0, stream>>>(h2, att_src2, att_dst2, a_src, a_dst, m_enc, denom);
    edge_max<<<EH_BLOCKS, 256, 0, stream>>>(ei, a_src, a_dst, m_enc);
    edge_denom<<<EH_BLOCKS, 256, 0, stream>>>(ei, a_src, a_dst, m_enc, denom);
    scatter_c16<<<EP / 4, 256, 0, stream>>>(ei, h2, a_src, a_dst, m_enc, denom, acc2);
    head_mean<<<(N_NODES * 16 + 255) / 256, 256, 0, stream>>>(acc2, bias2, out);
}

// Round 3
// 718.507 us; speedup vs baseline: 5.6147x; 5.6147x over previous
//
#include <hip/hip_runtime.h>

#define N_NODES 50000
#define N_EDGES 800000
#define EP (N_EDGES + N_NODES)   /* 850000 edges incl. self loops */
#define HEADS 8
#define NEG 0.2f

// ---- helpers -------------------------------------------------------------

__device__ __forceinline__ void get_edge(const int* __restrict__ ei, int e, int& s, int& d) {
    if (e < N_EDGES) { s = ei[e]; d = ei[N_EDGES + e]; }
    else             { s = d = e - N_EDGES; }           // self loop
}

__device__ __forceinline__ float lrelu(float v) { return v > 0.f ? v : NEG * v; }

// ---- CSR build: histogram -> exclusive scan -> fill ---------------------

__global__ void hist_kernel(const int* __restrict__ ei, int* __restrict__ cnt) {
    int e = blockIdx.x * 256 + threadIdx.x;
    if (e >= EP) return;
    int s, d; get_edge(ei, e, s, d);
    atomicAdd(&cnt[d], 1);
}

#define SCAN_T 1024
__global__ __launch_bounds__(SCAN_T) void scan_excl(int* __restrict__ cnt /* in: counts, out: cursor */,
                                                    int* __restrict__ row_start) {
    __shared__ int buf[SCAN_T];
    __shared__ int carry_s;
    const int tid = threadIdx.x;
    if (tid == 0) carry_s = 0;
    __syncthreads();
    for (int base = 0; base < N_NODES; base += SCAN_T) {
        int idx = base + tid;
        int v = (idx < N_NODES) ? cnt[idx] : 0;
        buf[tid] = v;
        __syncthreads();
        for (int off = 1; off < SCAN_T; off <<= 1) {   // Hillis-Steele inclusive
            int t = (tid >= off) ? buf[tid - off] : 0;
            __syncthreads();
            buf[tid] += t;
            __syncthreads();
        }
        int incl = buf[tid];
        int carry = carry_s;
        if (idx < N_NODES) {
            int excl = carry + incl - v;
            row_start[idx] = excl;
            cnt[idx] = excl;                            // becomes the fill cursor
        }
        __syncthreads();
        if (tid == SCAN_T - 1) carry_s = carry + incl;
        __syncthreads();
    }
    if (tid == 0) row_start[N_NODES] = carry_s;         // == EP
}

__global__ void fill_kernel(const int* __restrict__ ei, int* __restrict__ cursor,
                            unsigned short* __restrict__ csr) {
    int e = blockIdx.x * 256 + threadIdx.x;
    if (e >= EP) return;
    int s, d; get_edge(ei, e, s, d);
    int pos = atomicAdd(&cursor[d], 1);
    csr[pos] = (unsigned short)s;                       // N_NODES < 65536
}

// ---- GEMM: out[M,NC] = A[M,K] @ W[K,NC], 8 rows per block ---------------

template<int K, int NC>
__global__ __launch_bounds__(NC) void gemm_rows(const float* __restrict__ A,
                                                const float* __restrict__ W,
                                                float* __restrict__ out) {
    constexpr int ROWS = 8;
    __shared__ float a_lds[ROWS * K];
    const int row0 = blockIdx.x * ROWS;
    const int tid  = threadIdx.x;

    const float* Ap = A + (size_t)row0 * K;
    for (int i = tid; i < ROWS * K; i += NC) a_lds[i] = Ap[i];
    __syncthreads();

    float acc[ROWS];
#pragma unroll
    for (int r = 0; r < ROWS; r++) acc[r] = 0.f;

#pragma unroll 4
    for (int k = 0; k < K; k++) {
        float w = W[k * NC + tid];
#pragma unroll
        for (int r = 0; r < ROWS; r++) acc[r] = fmaf(a_lds[r * K + k], w, acc[r]);
    }
    float* o = out + (size_t)row0 * NC + tid;
#pragma unroll
    for (int r = 0; r < ROWS; r++) o[(size_t)r * NC] = acc[r];
}

// ---- per-(node,head) attention coefficients -----------------------------

template<int C>
__global__ void att_init(const float* __restrict__ h,
                         const float* __restrict__ att_s,
                         const float* __restrict__ att_d,
                         float* __restrict__ a_src, float* __restrict__ a_dst) {
    int t = blockIdx.x * blockDim.x + threadIdx.x;
    if (t >= N_NODES * HEADS) return;
    const int hh = t & 7;
    const float* hp = h + (size_t)(t >> 3) * (HEADS * C) + hh * C;
    float ss = 0.f, dd = 0.f;
#pragma unroll
    for (int c = 0; c < C; c++) {
        float v = hp[c];
        ss = fmaf(v, att_s[hh * C + c], ss);
        dd = fmaf(v, att_d[hh * C + c], dd);
    }
    a_src[t] = ss;
    a_dst[t] = dd;
}

// ---- fused segment softmax + aggregation: one block per dst node --------
// Phase 1: online-softmax stats (m, l) per head over the node's in-edges.
// Phase 2: thread t = feature f; acc += alpha[edge][f/C] * h[src][f], with
//          alpha staged per CH-edge chunk in LDS. Epilogue fused:
//          layer1 -> elu(acc + bias1[f]); layer2 -> head-mean + bias2.

template<int C, int T, bool LAYER2>
__global__ __launch_bounds__(T) void gat_agg(const int* __restrict__ row_start,
        const unsigned short* __restrict__ csr,
        const float* __restrict__ hfeat, const float* __restrict__ a_src,
        const float* __restrict__ a_dst, const float* __restrict__ bias,
        float* __restrict__ out) {
    constexpr int F  = 8 * C;    // == T
    constexpr int CH = T / 8;    // edges per chunk
    const int n   = blockIdx.x;
    const int tid = threadIdx.x;
    const int rs  = row_start[n];
    const int deg = row_start[n + 1] - rs;   // >= 1 (self loop)

    __shared__ float adst[8];
    __shared__ float red_m[T], red_l[T];
    __shared__ float al[CH][8];
    __shared__ unsigned short ssrc_l[CH];
    __shared__ float sm[8], sinv[8];

    if (tid < 8) adst[tid] = a_dst[n * 8 + tid];
    __syncthreads();

    // ---- phase 1: per-head online softmax stats ----
    const int h8 = tid & 7;
    float m = -1e30f, l = 0.f;
    for (int i = (tid >> 3); i < deg; i += CH) {
        int s = csr[rs + i];
        float e = lrelu(a_src[s * 8 + h8] + adst[h8]);
        float nm = fmaxf(m, e);
        l = l * __expf(m - nm) + __expf(e - nm);
        m = nm;
    }
    red_m[tid] = m; red_l[tid] = l;
    __syncthreads();
    for (int off = T / 2; off >= 8; off >>= 1) {   // off multiple of 8 -> same head
        if (tid < off) {
            float m2 = red_m[tid + off], l2 = red_l[tid + off];
            float m1 = red_m[tid],       l1 = red_l[tid];
            float nm = fmaxf(m1, m2);
            red_l[tid] = l1 * __expf(m1 - nm) + l2 * __expf(m2 - nm);
            red_m[tid] = nm;
        }
        __syncthreads();
    }
    if (tid < 8) { sm[tid] = red_m[tid]; sinv[tid] = 1.f / (red_l[tid] + 1e-16f); }
    __syncthreads();

    // ---- phase 2: weighted gather-accumulate ----
    const int hf = tid / C;
    float acc = 0.f;
    for (int c0 = 0; c0 < deg; c0 += CH) {
        int cnt = min(CH, deg - c0);
        if (tid < 8 * cnt) {
            int i = tid >> 3, h = tid & 7;
            int s = csr[rs + c0 + i];
            if (h == 0) ssrc_l[i] = (unsigned short)s;
            float e = lrelu(a_src[s * 8 + h] + adst[h]);
            al[i][h] = __expf(e - sm[h]) * sinv[h];
        }
        __syncthreads();
        for (int i = 0; i < cnt; i++)
            acc = fmaf(al[i][hf], hfeat[(size_t)ssrc_l[i] * F + tid], acc);
        __syncthreads();
    }

    // ---- fused epilogue ----
    if constexpr (!LAYER2) {
        float v = acc + bias[tid];
        out[(size_t)n * F + tid] = v > 0.f ? v : __expf(v) - 1.f;   // elu
    } else {
        red_m[tid] = acc;           // reuse as reduction scratch
        __syncthreads();
        if (tid < C) {
            float s2 = 0.f;
#pragma unroll
            for (int h = 0; h < 8; h++) s2 += red_m[h * C + tid];
            out[(size_t)n * C + tid] = s2 * 0.125f + bias[tid];
        }
    }
}

// ---- host ---------------------------------------------------------------

extern "C" void kernel_launch(void* const* d_in, const int* in_sizes, int n_in,
                              void* d_out, int out_size, void* d_ws, size_t ws_size,
                              hipStream_t stream) {
    const float* x        = (const float*)d_in[0];
    const int*   ei       = (const int*)d_in[1];
    const float* W1       = (const float*)d_in[2];
    const float* att_src1 = (const float*)d_in[3];
    const float* att_dst1 = (const float*)d_in[4];
    const float* bias1    = (const float*)d_in[5];
    const float* W2       = (const float*)d_in[6];
    const float* att_src2 = (const float*)d_in[7];
    const float* att_dst2 = (const float*)d_in[8];
    const float* bias2    = (const float*)d_in[9];
    float* out = (float*)d_out;

    char* ws = (char*)d_ws;
    const size_t SZ_NF = (size_t)N_NODES * 256 * 4;    // 51.2 MB
    float* h1 = (float*)(ws);                          // [N,256]; later h2 [N,128]
    float* h2 = (float*)(ws);
    float* x2 = (float*)(ws + SZ_NF);                  // [N,256] layer-1 output (post-elu)
    char*  aux = ws + 2 * SZ_NF;                       // 102.4 MB
    float*          a_src     = (float*)(aux);                  // [N,8]
    float*          a_dst     = (float*)(aux + 1600000);        // [N,8]
    int*            row_start = (int*)  (aux + 3200000);        // [N+1]
    int*            cnt       = (int*)  (aux + 3400064);        // [N] counts -> cursor
    unsigned short* csr       = (unsigned short*)(aux + 3600128); // [EP] u16 src ids
    // total ws use: ~107.6 MB

    const int E_BLOCKS  = (EP + 255) / 256;
    const int NH_BLOCKS = (N_NODES * HEADS + 255) / 256;

    // ---- CSR build (shared by both layers) ----
    hipMemsetAsync(cnt, 0, N_NODES * sizeof(int), stream);
    hist_kernel<<<E_BLOCKS, 256, 0, stream>>>(ei, cnt);
    scan_excl<<<1, SCAN_T, 0, stream>>>(cnt, row_start);
    fill_kernel<<<E_BLOCKS, 256, 0, stream>>>(ei, cnt, csr);

    // ---- layer 1 ----
    gemm_rows<256, 256><<<N_NODES / 8, 256, 0, stream>>>(x, W1, h1);
    att_init<32><<<NH_BLOCKS, 256, 0, stream>>>(h1, att_src1, att_dst1, a_src, a_dst);
    gat_agg<32, 256, false><<<N_NODES, 256, 0, stream>>>(row_start, csr, h1, a_src, a_dst, bias1, x2);

    // ---- layer 2 ----
    gemm_rows<256, 128><<<N_NODES / 8, 128, 0, stream>>>(x2, W2, h2);
    att_init<16><<<NH_BLOCKS, 256, 0, stream>>>(h2, att_src2, att_dst2, a_src, a_dst);
    gat_agg<16, 128, true><<<N_NODES, 128, 0, stream>>>(row_start, csr, h2, a_src, a_dst, bias2, out);
}

// Round 4
// 594.600 us; speedup vs baseline: 6.7847x; 1.2084x over previous
//
#include <hip/hip_runtime.h>

#define N_NODES 50000
#define N_EDGES 800000
#define EP (N_EDGES + N_NODES)   /* 850000 edges incl. self loops */
#define HEADS 8
#define NEG 0.2f

// ---- bf16 helpers (fp32 storage compression only; math stays fp32) ------

__device__ __forceinline__ float bf2f(unsigned short u) {
    return __uint_as_float(((unsigned)u) << 16);
}
__device__ __forceinline__ unsigned short f2bf(float f) {
    unsigned u = __float_as_uint(f);
    return (unsigned short)((u + 0x7FFFu + ((u >> 16) & 1u)) >> 16);  // RNE
}

__device__ __forceinline__ void get_edge(const int* __restrict__ ei, int e, int& s, int& d) {
    if (e < N_EDGES) { s = ei[e]; d = ei[N_EDGES + e]; }
    else             { s = d = e - N_EDGES; }           // self loop
}

__device__ __forceinline__ float lrelu(float v) { return v > 0.f ? v : NEG * v; }

// ---- CSR build: histogram -> exclusive scan -> fill ---------------------

__global__ void hist_kernel(const int* __restrict__ ei, int* __restrict__ cnt) {
    int e = blockIdx.x * 256 + threadIdx.x;
    if (e >= EP) return;
    int s, d; get_edge(ei, e, s, d);
    atomicAdd(&cnt[d], 1);
}

#define SCAN_T 1024
__global__ __launch_bounds__(SCAN_T) void scan_excl(int* __restrict__ cnt,
                                                    int* __restrict__ row_start) {
    __shared__ int wsum[16];
    __shared__ int carry_s;
    const int tid  = threadIdx.x;
    const int lane = tid & 63, wid = tid >> 6;
    if (tid == 0) carry_s = 0;
    __syncthreads();
    for (int base = 0; base < N_NODES; base += SCAN_T) {
        int idx = base + tid;
        int v0 = (idx < N_NODES) ? cnt[idx] : 0;
        int v = v0;
#pragma unroll
        for (int off = 1; off < 64; off <<= 1) {        // inclusive wave scan
            int t = __shfl_up(v, off);
            if (lane >= off) v += t;
        }
        if (lane == 63) wsum[wid] = v;
        __syncthreads();
        if (tid < 16) {                                  // scan the 16 wave sums
            int w = wsum[tid];
#pragma unroll
            for (int off = 1; off < 16; off <<= 1) {
                int t = __shfl_up(w, off);
                if (tid >= off) w += t;
            }
            wsum[tid] = w;
        }
        __syncthreads();
        int carry = carry_s;
        int excl = carry + (wid ? wsum[wid - 1] : 0) + v - v0;
        if (idx < N_NODES) { row_start[idx] = excl; cnt[idx] = excl; }
        __syncthreads();
        if (tid == 0) carry_s = carry + wsum[15];
        __syncthreads();
    }
    if (tid == 0) row_start[N_NODES] = carry_s;          // == EP
}

__global__ void fill_kernel(const int* __restrict__ ei, int* __restrict__ cursor,
                            unsigned short* __restrict__ csr) {
    int e = blockIdx.x * 256 + threadIdx.x;
    if (e >= EP) return;
    int s, d; get_edge(ei, e, s, d);
    int pos = atomicAdd(&cursor[d], 1);
    csr[pos] = (unsigned short)s;                       // N_NODES < 65536
}

// ---- tiled GEMM: out_bf16[M,NC] = A[M,256] @ W[256,NC] ------------------
// BM=64, BN=64, BK=32; 256 threads; 4x4 micro-tile per thread.

template<int NC>
__global__ __launch_bounds__(256) void gemm_tile(const float* __restrict__ A,
                                                 const float* __restrict__ W,
                                                 unsigned short* __restrict__ out) {
    constexpr int LDA = 66;            // pad: write conflicts 2-way (free), b64-aligned reads
    __shared__ float As[32][LDA];
    __shared__ float Bs[32][64];
    const int m0  = blockIdx.x * 64;
    const int n0  = blockIdx.y * 64;
    const int tid = threadIdx.x;
    const int tx  = tid & 15, ty = tid >> 4;

    const int lam = tid >> 2;          // A-loader: row 0..63
    const int lak = (tid & 3) * 8;     // A-loader: k offset 0,8,16,24
    const int lwk = tid >> 3;          // W-loader: k 0..31
    const int lwn = (tid & 7) * 8;     // W-loader: n offset 0..56

    const bool arow_ok = (m0 + lam) < N_NODES;
    float acc[4][4] = {};

    for (int k0 = 0; k0 < 256; k0 += 32) {
        float4 a0 = {0,0,0,0}, a1 = {0,0,0,0};
        if (arow_ok) {
            const float* ap = A + (size_t)(m0 + lam) * 256 + k0 + lak;
            a0 = *(const float4*)ap;
            a1 = *(const float4*)(ap + 4);
        }
        const float* wp = W + (size_t)(k0 + lwk) * NC + n0 + lwn;
        float4 b0 = *(const float4*)wp;
        float4 b1 = *(const float4*)(wp + 4);
        __syncthreads();
        As[lak + 0][lam] = a0.x; As[lak + 1][lam] = a0.y;
        As[lak + 2][lam] = a0.z; As[lak + 3][lam] = a0.w;
        As[lak + 4][lam] = a1.x; As[lak + 5][lam] = a1.y;
        As[lak + 6][lam] = a1.z; As[lak + 7][lam] = a1.w;
        *(float4*)&Bs[lwk][lwn]     = b0;
        *(float4*)&Bs[lwk][lwn + 4] = b1;
        __syncthreads();
#pragma unroll 8
        for (int kk = 0; kk < 32; kk++) {
            float av[4], bv[4];
            *(float2*)&av[0] = *(const float2*)&As[kk][ty * 4];
            *(float2*)&av[2] = *(const float2*)&As[kk][ty * 4 + 2];
            *(float4*)&bv[0] = *(const float4*)&Bs[kk][tx * 4];
#pragma unroll
            for (int i = 0; i < 4; i++)
#pragma unroll
                for (int j = 0; j < 4; j++)
                    acc[i][j] = fmaf(av[i], bv[j], acc[i][j]);
        }
    }
#pragma unroll
    for (int i = 0; i < 4; i++) {
        int m = m0 + ty * 4 + i;
        if (m < N_NODES) {
            ushort4 o;
            o.x = f2bf(acc[i][0]); o.y = f2bf(acc[i][1]);
            o.z = f2bf(acc[i][2]); o.w = f2bf(acc[i][3]);
            *(ushort4*)(out + (size_t)m * NC + n0 + tx * 4) = o;
        }
    }
}

// ---- per-(node,head) attention coefficients -----------------------------

template<int C>
__global__ void att_init(const unsigned short* __restrict__ h,
                         const float* __restrict__ att_s,
                         const float* __restrict__ att_d,
                         float* __restrict__ a_src, float* __restrict__ a_dst) {
    int t = blockIdx.x * blockDim.x + threadIdx.x;
    if (t >= N_NODES * HEADS) return;
    const int hh = t & 7;
    const unsigned short* hp = h + (size_t)(t >> 3) * (HEADS * C) + hh * C;
    float ss = 0.f, dd = 0.f;
#pragma unroll
    for (int c = 0; c < C; c++) {
        float v = bf2f(hp[c]);
        ss = fmaf(v, att_s[hh * C + c], ss);
        dd = fmaf(v, att_d[hh * C + c], dd);
    }
    a_src[t] = ss;
    a_dst[t] = dd;
}

// ---- fused segment softmax + aggregation: one block per dst node --------

template<int C, int T, bool LAYER2>
__global__ __launch_bounds__(T) void gat_agg(const int* __restrict__ row_start,
        const unsigned short* __restrict__ csr,
        const unsigned short* __restrict__ hfeat, const float* __restrict__ a_src,
        const float* __restrict__ a_dst, const float* __restrict__ bias,
        float* __restrict__ out) {
    constexpr int F  = 8 * C;    // == T
    constexpr int CH = T / 8;    // edges per chunk
    const int n   = blockIdx.x;
    const int tid = threadIdx.x;
    const int rs  = row_start[n];
    const int deg = row_start[n + 1] - rs;   // >= 1 (self loop)

    __shared__ float adst[8];
    __shared__ float red_m[T], red_l[T];
    __shared__ float al[CH][8];
    __shared__ unsigned short ssrc_l[CH];
    __shared__ float sm[8], sinv[8];

    if (tid < 8) adst[tid] = a_dst[n * 8 + tid];
    __syncthreads();

    // ---- phase 1: per-head online softmax stats ----
    const int h8 = tid & 7;
    float m = -1e30f, l = 0.f;
    for (int i = (tid >> 3); i < deg; i += CH) {
        int s = csr[rs + i];
        float e = lrelu(a_src[s * 8 + h8] + adst[h8]);
        float nm = fmaxf(m, e);
        l = l * __expf(m - nm) + __expf(e - nm);
        m = nm;
    }
    red_m[tid] = m; red_l[tid] = l;
    __syncthreads();
    for (int off = T / 2; off >= 8; off >>= 1) {   // off multiple of 8 -> same head
        if (tid < off) {
            float m2 = red_m[tid + off], l2 = red_l[tid + off];
            float m1 = red_m[tid],       l1 = red_l[tid];
            float nm = fmaxf(m1, m2);
            red_l[tid] = l1 * __expf(m1 - nm) + l2 * __expf(m2 - nm);
            red_m[tid] = nm;
        }
        __syncthreads();
    }
    if (tid < 8) { sm[tid] = red_m[tid]; sinv[tid] = 1.f / (red_l[tid] + 1e-16f); }
    __syncthreads();

    // ---- phase 2: weighted gather-accumulate (bf16 rows, fp32 acc) ----
    const int hf = tid / C;
    float acc = 0.f;
    for (int c0 = 0; c0 < deg; c0 += CH) {
        int cnt = min(CH, deg - c0);
        if (tid < 8 * cnt) {
            int i = tid >> 3, h = tid & 7;
            int s = csr[rs + c0 + i];
            if (h == 0) ssrc_l[i] = (unsigned short)s;
            float e = lrelu(a_src[s * 8 + h] + adst[h]);
            al[i][h] = __expf(e - sm[h]) * sinv[h];
        }
        __syncthreads();
        for (int i = 0; i < cnt; i++)
            acc = fmaf(al[i][hf], bf2f(hfeat[(size_t)ssrc_l[i] * F + tid]), acc);
        __syncthreads();
    }

    // ---- fused epilogue ----
    if constexpr (!LAYER2) {
        float v = acc + bias[tid];
        out[(size_t)n * F + tid] = v > 0.f ? v : __expf(v) - 1.f;   // elu
    } else {
        red_m[tid] = acc;
        __syncthreads();
        if (tid < C) {
            float s2 = 0.f;
#pragma unroll
            for (int h = 0; h < 8; h++) s2 += red_m[h * C + tid];
            out[(size_t)n * C + tid] = s2 * 0.125f + bias[tid];
        }
    }
}

// ---- host ---------------------------------------------------------------

extern "C" void kernel_launch(void* const* d_in, const int* in_sizes, int n_in,
                              void* d_out, int out_size, void* d_ws, size_t ws_size,
                              hipStream_t stream) {
    const float* x        = (const float*)d_in[0];
    const int*   ei       = (const int*)d_in[1];
    const float* W1       = (const float*)d_in[2];
    const float* att_src1 = (const float*)d_in[3];
    const float* att_dst1 = (const float*)d_in[4];
    const float* bias1    = (const float*)d_in[5];
    const float* W2       = (const float*)d_in[6];
    const float* att_src2 = (const float*)d_in[7];
    const float* att_dst2 = (const float*)d_in[8];
    const float* bias2    = (const float*)d_in[9];
    float* out = (float*)d_out;

    char* ws = (char*)d_ws;
    unsigned short* h1 = (unsigned short*)(ws);                  // bf16 [N,256] = 25.6 MB
    unsigned short* h2 = (unsigned short*)(ws);                  // bf16 [N,128] overlays h1
    float* x2 = (float*)(ws + 32ull * 1024 * 1024);              // fp32 [N,256] = 51.2 MB
    char*  aux = ws + 90ull * 1024 * 1024;
    float*          a_src     = (float*)(aux);                   // [N,8]
    float*          a_dst     = (float*)(aux + 1600000);         // [N,8]
    int*            row_start = (int*)  (aux + 3200000);         // [N+1]
    int*            cnt       = (int*)  (aux + 3400064);         // [N]
    unsigned short* csr       = (unsigned short*)(aux + 3600128);// [EP] u16

    const int E_BLOCKS  = (EP + 255) / 256;
    const int NH_BLOCKS = (N_NODES * HEADS + 255) / 256;
    const int MT = (N_NODES + 63) / 64;   // 782 row-tiles

    // ---- CSR build (shared by both layers) ----
    hipMemsetAsync(cnt, 0, N_NODES * sizeof(int), stream);
    hist_kernel<<<E_BLOCKS, 256, 0, stream>>>(ei, cnt);
    scan_excl<<<1, SCAN_T, 0, stream>>>(cnt, row_start);
    fill_kernel<<<E_BLOCKS, 256, 0, stream>>>(ei, cnt, csr);

    // ---- layer 1 ----
    gemm_tile<256><<<dim3(MT, 4), 256, 0, stream>>>(x, W1, h1);
    att_init<32><<<NH_BLOCKS, 256, 0, stream>>>(h1, att_src1, att_dst1, a_src, a_dst);
    gat_agg<32, 256, false><<<N_NODES, 256, 0, stream>>>(row_start, csr, h1, a_src, a_dst, bias1, x2);

    // ---- layer 2 ----
    gemm_tile<128><<<dim3(MT, 2), 256, 0, stream>>>(x2, W2, h2);
    att_init<16><<<NH_BLOCKS, 256, 0, stream>>>(h2, att_src2, att_dst2, a_src, a_dst);
    gat_agg<16, 128, true><<<N_NODES, 128, 0, stream>>>(row_start, csr, h2, a_src, a_dst, bias2, out);
}

// Round 5
// 512.449 us; speedup vs baseline: 7.8724x; 1.1603x over previous
//
#include <hip/hip_runtime.h>

#define N_NODES 50000
#define N_EDGES 800000
#define EP (N_EDGES + N_NODES)   /* 850000 edges incl. self loops */
#define HEADS 8
#define NEG 0.2f

typedef __attribute__((ext_vector_type(8))) short bf16x8;
typedef __attribute__((ext_vector_type(4))) float f32x4;

// ---- bf16 helpers (storage compression; math stays fp32) ----------------

__device__ __forceinline__ float bf2f(unsigned short u) {
    return __uint_as_float(((unsigned)u) << 16);
}
__device__ __forceinline__ unsigned short f2bf(float f) {
    unsigned u = __float_as_uint(f);
    return (unsigned short)((u + 0x7FFFu + ((u >> 16) & 1u)) >> 16);  // RNE
}

__device__ __forceinline__ void get_edge(const int* __restrict__ ei, int e, int& s, int& d) {
    if (e < N_EDGES) { s = ei[e]; d = ei[N_EDGES + e]; }
    else             { s = d = e - N_EDGES; }           // self loop
}

__device__ __forceinline__ float lrelu(float v) { return v > 0.f ? v : NEG * v; }

// ---- CSR build: histogram -> exclusive scan -> fill ---------------------

__global__ void hist_kernel(const int* __restrict__ ei, int* __restrict__ cnt) {
    int e = blockIdx.x * 256 + threadIdx.x;
    if (e >= EP) return;
    int s, d; get_edge(ei, e, s, d);
    atomicAdd(&cnt[d], 1);
}

#define SCAN_T 1024
__global__ __launch_bounds__(SCAN_T) void scan_excl(int* __restrict__ cnt,
                                                    int* __restrict__ row_start) {
    __shared__ int wsum[16];
    __shared__ int carry_s;
    const int tid  = threadIdx.x;
    const int lane = tid & 63, wid = tid >> 6;
    if (tid == 0) carry_s = 0;
    __syncthreads();
    for (int base = 0; base < N_NODES; base += SCAN_T) {
        int idx = base + tid;
        int v0 = (idx < N_NODES) ? cnt[idx] : 0;
        int v = v0;
#pragma unroll
        for (int off = 1; off < 64; off <<= 1) {
            int t = __shfl_up(v, off);
            if (lane >= off) v += t;
        }
        if (lane == 63) wsum[wid] = v;
        __syncthreads();
        if (tid < 16) {
            int w = wsum[tid];
#pragma unroll
            for (int off = 1; off < 16; off <<= 1) {
                int t = __shfl_up(w, off);
                if (tid >= off) w += t;
            }
            wsum[tid] = w;
        }
        __syncthreads();
        int carry = carry_s;
        int excl = carry + (wid ? wsum[wid - 1] : 0) + v - v0;
        if (idx < N_NODES) { row_start[idx] = excl; cnt[idx] = excl; }
        __syncthreads();
        if (tid == 0) carry_s = carry + wsum[15];
        __syncthreads();
    }
    if (tid == 0) row_start[N_NODES] = carry_s;
}

__global__ void fill_kernel(const int* __restrict__ ei, int* __restrict__ cursor,
                            unsigned short* __restrict__ csr) {
    int e = blockIdx.x * 256 + threadIdx.x;
    if (e >= EP) return;
    int s, d; get_edge(ei, e, s, d);
    int pos = atomicAdd(&cursor[d], 1);
    csr[pos] = (unsigned short)s;
}

// ---- MFMA bf16 GEMM: out_bf16[M,NC] = A_fp32[M,256] @ W_fp32[256,NC] ----
// BM=BN=BK=64; 256 threads = 4 waves in 2x2; wave tile 32x32 = 2x2 mfma.
// A staged [m][k] bf16, W staged transposed [n][k] bf16 (B^T layout), rows
// padded to 72 shorts (144 B, 16B-aligned) for ds_read_b128 frag loads.

template<int NC>
__global__ __launch_bounds__(256) void gemm_mfma(const float* __restrict__ A,
                                                 const float* __restrict__ W,
                                                 unsigned short* __restrict__ out) {
    constexpr int LDT = 72;
    __shared__ unsigned short As[64 * LDT];
    __shared__ unsigned short Bs[64 * LDT];
    const int m0 = blockIdx.x * 64, n0 = blockIdx.y * 64;
    const int tid  = threadIdx.x;
    const int wave = tid >> 6, lane = tid & 63;
    const int wm = (wave & 1) * 32, wn = (wave >> 1) * 32;
    const int col = lane & 15, quad = lane >> 4;

    const int am = tid >> 2;            // A stager: row 0..63
    const int ak = (tid & 3) * 4;       // A stager: k base {0,4,8,12} (+16*i)
    const int bn = tid & 63;            // B stager: col n 0..63
    const int bk = (tid >> 6) * 2;      // B stager: k pair base {0,2,4,6} (+8*i)

    const bool mok = (m0 + am) < N_NODES;
    f32x4 acc[2][2] = {};

    for (int k0 = 0; k0 < 256; k0 += 64) {
        float4 av[4];
#pragma unroll
        for (int i = 0; i < 4; i++) {
            av[i] = make_float4(0.f, 0.f, 0.f, 0.f);
            if (mok) av[i] = *(const float4*)(A + (size_t)(m0 + am) * 256 + k0 + ak + i * 16);
        }
        float bv[16];
#pragma unroll
        for (int i = 0; i < 8; i++) {
            bv[2*i]   = W[(size_t)(k0 + bk + i * 8)     * NC + n0 + bn];
            bv[2*i+1] = W[(size_t)(k0 + bk + i * 8 + 1) * NC + n0 + bn];
        }
        __syncthreads();   // prior compute done before overwriting LDS
#pragma unroll
        for (int i = 0; i < 4; i++) {
            ushort4 o;
            o.x = f2bf(av[i].x); o.y = f2bf(av[i].y);
            o.z = f2bf(av[i].z); o.w = f2bf(av[i].w);
            *(ushort4*)&As[am * LDT + ak + i * 16] = o;
        }
#pragma unroll
        for (int i = 0; i < 8; i++) {
            unsigned pk = (unsigned)f2bf(bv[2*i]) | ((unsigned)f2bf(bv[2*i+1]) << 16);
            *(unsigned*)&Bs[bn * LDT + bk + i * 8] = pk;
        }
        __syncthreads();
#pragma unroll
        for (int ks = 0; ks < 64; ks += 32) {
            bf16x8 af[2], bfr[2];
#pragma unroll
            for (int mi = 0; mi < 2; mi++)
                af[mi] = *(const bf16x8*)&As[(wm + mi * 16 + col) * LDT + ks + quad * 8];
#pragma unroll
            for (int ni = 0; ni < 2; ni++)
                bfr[ni] = *(const bf16x8*)&Bs[(wn + ni * 16 + col) * LDT + ks + quad * 8];
#pragma unroll
            for (int mi = 0; mi < 2; mi++)
#pragma unroll
                for (int ni = 0; ni < 2; ni++)
                    acc[mi][ni] = __builtin_amdgcn_mfma_f32_16x16x32_bf16(
                        af[mi], bfr[ni], acc[mi][ni], 0, 0, 0);
        }
    }
    // C/D layout: col = lane&15, row = quad*4 + reg
#pragma unroll
    for (int mi = 0; mi < 2; mi++)
#pragma unroll
        for (int ni = 0; ni < 2; ni++)
#pragma unroll
            for (int r = 0; r < 4; r++) {
                int m = m0 + wm + mi * 16 + quad * 4 + r;
                if (m < N_NODES)
                    out[(size_t)m * NC + n0 + wn + ni * 16 + col] = f2bf(acc[mi][ni][r]);
            }
}

// ---- per-(node,head) attention coefficients -----------------------------

template<int C>
__global__ void att_init(const unsigned short* __restrict__ h,
                         const float* __restrict__ att_s,
                         const float* __restrict__ att_d,
                         float* __restrict__ a_src, float* __restrict__ a_dst) {
    int t = blockIdx.x * blockDim.x + threadIdx.x;
    if (t >= N_NODES * HEADS) return;
    const int hh = t & 7;
    const unsigned short* hp = h + (size_t)(t >> 3) * (HEADS * C) + hh * C;
    float ss = 0.f, dd = 0.f;
#pragma unroll
    for (int c = 0; c < C; c++) {
        float v = bf2f(hp[c]);
        ss = fmaf(v, att_s[hh * C + c], ss);
        dd = fmaf(v, att_d[hh * C + c], dd);
    }
    a_src[t] = ss;
    a_dst[t] = dd;
}

// ---- fused softmax + aggregation: ONE WAVE per dst node, zero barriers --
// Phase 1: lane = (edge-slot io=l>>3, head h=l&7), online softmax, butterfly
//          shuffle reduce over io (xor 8,16,32).
// Phase 2: whole wave gathers one bf16 row/edge; lane covers VF feats of
//          head l>>3; alpha recomputed in-register.

template<int C, bool LAYER2>
__global__ __launch_bounds__(256) void gat_agg_wave(const int* __restrict__ row_start,
        const unsigned short* __restrict__ csr,
        const unsigned short* __restrict__ hfeat, const float* __restrict__ a_src,
        const float* __restrict__ a_dst, const float* __restrict__ bias,
        float* __restrict__ out) {
    constexpr int F  = 8 * C;          // 256 or 128
    constexpr int VF = F / 64;         // feats per lane: 4 or 2
    const int n    = blockIdx.x * 4 + (threadIdx.x >> 6);
    const int lane = threadIdx.x & 63;
    if (n >= N_NODES) return;

    const int rs  = row_start[n];
    const int deg = row_start[n + 1] - rs;     // >= 1

    // ---- phase 1 ----
    const int h  = lane & 7;
    const int io = lane >> 3;
    const float adst_h = a_dst[n * 8 + h];
    float m = -1e30f, l = 0.f;
    for (int i = io; i < deg; i += 8) {
        int s = csr[rs + i];
        float e = lrelu(a_src[s * 8 + h] + adst_h);
        float nm = fmaxf(m, e);
        l = l * __expf(m - nm) + __expf(e - nm);
        m = nm;
    }
#pragma unroll
    for (int off = 8; off <= 32; off <<= 1) {
        float m2 = __shfl_xor(m, off), l2 = __shfl_xor(l, off);
        float nm = fmaxf(m, m2);
        l = l * __expf(m - nm) + l2 * __expf(m2 - nm);
        m = nm;
    }
    float inv = 1.f / (l + 1e-16f);
    // redistribute: phase-2 head for this lane is hf = lane>>3; lane hf holds its stats
    const int hf = lane >> 3;
    const float mf    = __shfl(m, hf);
    const float invf  = __shfl(inv, hf);
    const float adstf = __shfl(adst_h, hf);

    // ---- phase 2 ----
    float acc[VF] = {};
    for (int e = 0; e < deg; e++) {
        int s = __builtin_amdgcn_readfirstlane((int)csr[rs + e]);
        float al = __expf(lrelu(a_src[s * 8 + hf] + adstf) - mf) * invf;
        if constexpr (!LAYER2) {
            ushort4 hv = *(const ushort4*)(hfeat + (size_t)s * F + lane * 4);
            acc[0] = fmaf(al, bf2f(hv.x), acc[0]);
            acc[1] = fmaf(al, bf2f(hv.y), acc[1]);
            acc[2] = fmaf(al, bf2f(hv.z), acc[2]);
            acc[3] = fmaf(al, bf2f(hv.w), acc[3]);
        } else {
            ushort2 hv = *(const ushort2*)(hfeat + (size_t)s * F + lane * 2);
            acc[0] = fmaf(al, bf2f(hv.x), acc[0]);
            acc[1] = fmaf(al, bf2f(hv.y), acc[1]);
        }
    }

    // ---- epilogue ----
    if constexpr (!LAYER2) {
        float4 o;
        float* op = (float*)&o;
#pragma unroll
        for (int j = 0; j < 4; j++) {
            float v = acc[j] + bias[lane * 4 + j];
            op[j] = v > 0.f ? v : __expf(v) - 1.f;     // elu
        }
        *(float4*)(out + (size_t)n * F + lane * 4) = o;
    } else {
        // head-mean: sum over the 8 head-lanes sharing this c-pair
#pragma unroll
        for (int off = 8; off <= 32; off <<= 1) {
            acc[0] += __shfl_xor(acc[0], off);
            acc[1] += __shfl_xor(acc[1], off);
        }
        if (lane < 8) {
            float2 o;
            o.x = acc[0] * 0.125f + bias[lane * 2];
            o.y = acc[1] * 0.125f + bias[lane * 2 + 1];
            *(float2*)(out + (size_t)n * 16 + lane * 2) = o;
        }
    }
}

// ---- host ---------------------------------------------------------------

extern "C" void kernel_launch(void* const* d_in, const int* in_sizes, int n_in,
                              void* d_out, int out_size, void* d_ws, size_t ws_size,
                              hipStream_t stream) {
    const float* x        = (const float*)d_in[0];
    const int*   ei       = (const int*)d_in[1];
    const float* W1       = (const float*)d_in[2];
    const float* att_src1 = (const float*)d_in[3];
    const float* att_dst1 = (const float*)d_in[4];
    const float* bias1    = (const float*)d_in[5];
    const float* W2       = (const float*)d_in[6];
    const float* att_src2 = (const float*)d_in[7];
    const float* att_dst2 = (const float*)d_in[8];
    const float* bias2    = (const float*)d_in[9];
    float* out = (float*)d_out;

    char* ws = (char*)d_ws;
    unsigned short* h1 = (unsigned short*)(ws);                  // bf16 [N,256]
    unsigned short* h2 = (unsigned short*)(ws);                  // bf16 [N,128] overlays
    float* x2 = (float*)(ws + 32ull * 1024 * 1024);              // fp32 [N,256]
    char*  aux = ws + 90ull * 1024 * 1024;
    float*          a_src     = (float*)(aux);
    float*          a_dst     = (float*)(aux + 1600000);
    int*            row_start = (int*)  (aux + 3200000);
    int*            cnt       = (int*)  (aux + 3400064);
    unsigned short* csr       = (unsigned short*)(aux + 3600128);

    const int E_BLOCKS  = (EP + 255) / 256;
    const int NH_BLOCKS = (N_NODES * HEADS + 255) / 256;
    const int MT = (N_NODES + 63) / 64;     // 782
    const int AGG_BLOCKS = (N_NODES + 3) / 4;

    // ---- CSR build (shared by both layers) ----
    hipMemsetAsync(cnt, 0, N_NODES * sizeof(int), stream);
    hist_kernel<<<E_BLOCKS, 256, 0, stream>>>(ei, cnt);
    scan_excl<<<1, SCAN_T, 0, stream>>>(cnt, row_start);
    fill_kernel<<<E_BLOCKS, 256, 0, stream>>>(ei, cnt, csr);

    // ---- layer 1 ----
    gemm_mfma<256><<<dim3(MT, 4), 256, 0, stream>>>(x, W1, h1);
    att_init<32><<<NH_BLOCKS, 256, 0, stream>>>(h1, att_src1, att_dst1, a_src, a_dst);
    gat_agg_wave<32, false><<<AGG_BLOCKS, 256, 0, stream>>>(row_start, csr, h1, a_src, a_dst, bias1, x2);

    // ---- layer 2 ----
    gemm_mfma<128><<<dim3(MT, 2), 256, 0, stream>>>(x2, W2, h2);
    att_init<16><<<NH_BLOCKS, 256, 0, stream>>>(h2, att_src2, att_dst2, a_src, a_dst);
    gat_agg_wave<16, true><<<AGG_BLOCKS, 256, 0, stream>>>(row_start, csr, h2, a_src, a_dst, bias2, out);
}

// Round 6
// 390.757 us; speedup vs baseline: 10.3240x; 1.3114x over previous
//
#include <hip/hip_runtime.h>

#define N_NODES 50000
#define N_EDGES 800000
#define EP (N_EDGES + N_NODES)   /* 850000 edges incl. self loops */
#define HEADS 8
#define NEG 0.2f

typedef __attribute__((ext_vector_type(8))) short bf16x8;
typedef __attribute__((ext_vector_type(8))) unsigned short u16x8;
typedef __attribute__((ext_vector_type(4))) float f32x4;

// ---- bf16 helpers (storage compression; math stays fp32) ----------------

__device__ __forceinline__ float bf2f(unsigned short u) {
    return __uint_as_float(((unsigned)u) << 16);
}
__device__ __forceinline__ unsigned short f2bf(float f) {
    unsigned u = __float_as_uint(f);
    return (unsigned short)((u + 0x7FFFu + ((u >> 16) & 1u)) >> 16);  // RNE
}

__device__ __forceinline__ void get_edge(const int* __restrict__ ei, int e, int& s, int& d) {
    if (e < N_EDGES) { s = ei[e]; d = ei[N_EDGES + e]; }
    else             { s = d = e - N_EDGES; }           // self loop
}

__device__ __forceinline__ float lrelu(float v) { return v > 0.f ? v : NEG * v; }

// ---- prep: x -> bf16, W1/W2 -> bf16 transposed [n][k] -------------------

#define PREP_X4 3200000                       /* 12.8M floats / 4 */
__global__ void prep_kernel(const float* __restrict__ x, const float* __restrict__ W1,
                            const float* __restrict__ W2, unsigned short* __restrict__ xb,
                            unsigned short* __restrict__ W1T, unsigned short* __restrict__ W2T) {
    int t = blockIdx.x * 256 + threadIdx.x;
    if (t < PREP_X4) {
        float4 v = ((const float4*)x)[t];
        ushort4 o;
        o.x = f2bf(v.x); o.y = f2bf(v.y); o.z = f2bf(v.z); o.w = f2bf(v.w);
        ((ushort4*)xb)[t] = o;
    } else if (t < PREP_X4 + 65536) {
        int u = t - PREP_X4; int k = u >> 8, n = u & 255;
        W1T[n * 256 + k] = f2bf(W1[k * 256 + n]);
    } else if (t < PREP_X4 + 65536 + 32768) {
        int u = t - (PREP_X4 + 65536); int k = u >> 7, n = u & 127;
        W2T[n * 256 + k] = f2bf(W2[k * 128 + n]);
    }
}

// ---- CSR build: histogram -> exclusive scan -> fill ---------------------

__global__ void hist_kernel(const int* __restrict__ ei, int* __restrict__ cnt) {
    int e = blockIdx.x * 256 + threadIdx.x;
    if (e >= EP) return;
    int s, d; get_edge(ei, e, s, d);
    atomicAdd(&cnt[d], 1);
}

#define SCAN_T 1024
__global__ __launch_bounds__(SCAN_T) void scan_excl(int* __restrict__ cnt,
                                                    int* __restrict__ row_start) {
    __shared__ int wsum[16];
    __shared__ int carry_s;
    const int tid  = threadIdx.x;
    const int lane = tid & 63, wid = tid >> 6;
    if (tid == 0) carry_s = 0;
    __syncthreads();
    for (int base = 0; base < N_NODES; base += SCAN_T) {
        int idx = base + tid;
        int v0 = (idx < N_NODES) ? cnt[idx] : 0;
        int v = v0;
#pragma unroll
        for (int off = 1; off < 64; off <<= 1) {
            int t = __shfl_up(v, off);
            if (lane >= off) v += t;
        }
        if (lane == 63) wsum[wid] = v;
        __syncthreads();
        if (tid < 16) {
            int w = wsum[tid];
#pragma unroll
            for (int off = 1; off < 16; off <<= 1) {
                int t = __shfl_up(w, off);
                if (tid >= off) w += t;
            }
            wsum[tid] = w;
        }
        __syncthreads();
        int carry = carry_s;
        int excl = carry + (wid ? wsum[wid - 1] : 0) + v - v0;
        if (idx < N_NODES) { row_start[idx] = excl; cnt[idx] = excl; }
        __syncthreads();
        if (tid == 0) carry_s = carry + wsum[15];
        __syncthreads();
    }
    if (tid == 0) row_start[N_NODES] = carry_s;
}

__global__ void fill_kernel(const int* __restrict__ ei, int* __restrict__ cursor,
                            unsigned short* __restrict__ csr) {
    int e = blockIdx.x * 256 + threadIdx.x;
    if (e >= EP) return;
    int s, d; get_edge(ei, e, s, d);
    int pos = atomicAdd(&cursor[d], 1);
    csr[pos] = (unsigned short)s;
}

// ---- MFMA bf16 GEMM: out_bf16[M,NC] = A_bf16[M,256] @ WT_bf16[NC,256]^T -
// BM=BN=64, BK=64; 4 waves 2x2; Bs staged full-K once; XOR-swizzled LDS
// (chunk c of row r stored at c^(r&7)) -> conflict-free ds_read_b128, no pad.

template<int NC>
__global__ __launch_bounds__(256) void gemm_bf16(const unsigned short* __restrict__ A,
                                                 const unsigned short* __restrict__ WT,
                                                 unsigned short* __restrict__ out) {
    __shared__ unsigned short Bs[64 * 256];   // [n][k] 32 KB
    __shared__ unsigned short As[64 * 64];    // [m][k-slab] 8 KB
    const int m0 = blockIdx.x * 64, n0 = blockIdx.y * 64;
    const int tid  = threadIdx.x;
    const int wave = tid >> 6, lane = tid & 63;
    const int wm = (wave & 1) * 32, wn = (wave >> 1) * 32;
    const int col = lane & 15, quad = lane >> 4;

    const int sr = tid >> 2;        // stager row 0..63
    const int sc = tid & 3;         // stager chunk phase 0..3

    // ---- stage B full-K ----
#pragma unroll
    for (int j = 0; j < 8; j++) {
        int chunk = sc + j * 4;                      // 0..31
        u16x8 v = *(const u16x8*)(WT + (size_t)(n0 + sr) * 256 + chunk * 8);
        *(u16x8*)&Bs[sr * 256 + ((chunk & 24) | ((chunk ^ sr) & 7)) * 8] = v;
    }

    const bool mok = (m0 + sr) < N_NODES;
    f32x4 acc[2][2] = {};

    for (int k0 = 0; k0 < 256; k0 += 64) {
        u16x8 av[2] = {};
#pragma unroll
        for (int j = 0; j < 2; j++) {
            int chunk = sc + j * 4;                  // 0..7
            if (mok) av[j] = *(const u16x8*)(A + (size_t)(m0 + sr) * 256 + k0 + chunk * 8);
        }
        __syncthreads();                             // prior mfma reads done
#pragma unroll
        for (int j = 0; j < 2; j++) {
            int chunk = sc + j * 4;
            *(u16x8*)&As[sr * 64 + (chunk ^ (sr & 7)) * 8] = av[j];
        }
        __syncthreads();                             // As (+Bs on iter0) visible
#pragma unroll
        for (int ks = 0; ks < 64; ks += 32) {
            bf16x8 af[2], bfr[2];
#pragma unroll
            for (int mi = 0; mi < 2; mi++) {
                int r = wm + mi * 16 + col;
                int ca = (ks >> 3) + quad;           // 0..7
                af[mi] = *(const bf16x8*)&As[r * 64 + (ca ^ (r & 7)) * 8];
            }
#pragma unroll
            for (int ni = 0; ni < 2; ni++) {
                int r = wn + ni * 16 + col;
                int cb = ((k0 + ks) >> 3) + quad;    // 0..31
                bfr[ni] = *(const bf16x8*)&Bs[r * 256 + ((cb & 24) | ((cb ^ r) & 7)) * 8];
            }
#pragma unroll
            for (int mi = 0; mi < 2; mi++)
#pragma unroll
                for (int ni = 0; ni < 2; ni++)
                    acc[mi][ni] = __builtin_amdgcn_mfma_f32_16x16x32_bf16(
                        af[mi], bfr[ni], acc[mi][ni], 0, 0, 0);
        }
    }
    // C/D layout: col = lane&15 (n), row = quad*4 + reg (m)
#pragma unroll
    for (int mi = 0; mi < 2; mi++)
#pragma unroll
        for (int ni = 0; ni < 2; ni++)
#pragma unroll
            for (int r = 0; r < 4; r++) {
                int m = m0 + wm + mi * 16 + quad * 4 + r;
                if (m < N_NODES)
                    out[(size_t)m * NC + n0 + wn + ni * 16 + col] = f2bf(acc[mi][ni][r]);
            }
}

// ---- per-(node,head) attention coefficients -----------------------------

template<int C>
__global__ void att_init(const unsigned short* __restrict__ h,
                         const float* __restrict__ att_s,
                         const float* __restrict__ att_d,
                         float* __restrict__ a_src, float* __restrict__ a_dst) {
    int t = blockIdx.x * blockDim.x + threadIdx.x;
    if (t >= N_NODES * HEADS) return;
    const int hh = t & 7;
    const unsigned short* hp = h + (size_t)(t >> 3) * (HEADS * C) + hh * C;
    float ss = 0.f, dd = 0.f;
#pragma unroll
    for (int c4 = 0; c4 < C; c4 += 4) {
        ushort4 hv = *(const ushort4*)(hp + c4);
        float v0 = bf2f(hv.x), v1 = bf2f(hv.y), v2 = bf2f(hv.z), v3 = bf2f(hv.w);
        ss = fmaf(v0, att_s[hh * C + c4 + 0], ss);
        ss = fmaf(v1, att_s[hh * C + c4 + 1], ss);
        ss = fmaf(v2, att_s[hh * C + c4 + 2], ss);
        ss = fmaf(v3, att_s[hh * C + c4 + 3], ss);
        dd = fmaf(v0, att_d[hh * C + c4 + 0], dd);
        dd = fmaf(v1, att_d[hh * C + c4 + 1], dd);
        dd = fmaf(v2, att_d[hh * C + c4 + 2], dd);
        dd = fmaf(v3, att_d[hh * C + c4 + 3], dd);
    }
    a_src[t] = ss;
    a_dst[t] = dd;
}

// ---- fused single-pass softmax+aggregate: ONE WAVE per node -------------
// No max-subtraction (|e| <= ~5 analytically -> exp safe in fp32):
// acc += exp(e)*h[src], den += exp(e); final = acc/den. Edge ids preloaded
// per 64-chunk (coalesced) and broadcast via __shfl; gathers batched x4 for
// memory-level parallelism.

template<int C, bool LAYER2>
__global__ __launch_bounds__(256) void gat_agg_fused(const int* __restrict__ row_start,
        const unsigned short* __restrict__ csr,
        const unsigned short* __restrict__ hfeat, const float* __restrict__ a_src,
        const float* __restrict__ a_dst, const float* __restrict__ bias,
        void* __restrict__ outp) {
    constexpr int F  = 8 * C;          // 256 or 128
    constexpr int VF = F / 64;         // feats per lane: 4 or 2
    const int n    = blockIdx.x * 4 + (threadIdx.x >> 6);
    const int lane = threadIdx.x & 63;
    if (n >= N_NODES) return;

    const int rs  = row_start[n];
    const int deg = row_start[n + 1] - rs;     // >= 1 (self loop)
    const int hf  = lane >> 3;                 // this lane's head
    const float adstf = a_dst[n * 8 + hf];

    float acc[VF] = {};
    float den = 0.f;

    for (int c0 = 0; c0 < deg; c0 += 64) {
        const int cnt = min(64, deg - c0);
        int myid = (lane < cnt) ? (int)csr[rs + c0 + lane] : 0;
        int e = 0;
        for (; e + 4 <= cnt; e += 4) {
            int s0 = __shfl(myid, e + 0), s1 = __shfl(myid, e + 1);
            int s2 = __shfl(myid, e + 2), s3 = __shfl(myid, e + 3);
            float as0 = a_src[s0 * 8 + hf], as1 = a_src[s1 * 8 + hf];
            float as2 = a_src[s2 * 8 + hf], as3 = a_src[s3 * 8 + hf];
            if constexpr (!LAYER2) {
                ushort4 v0 = *(const ushort4*)(hfeat + (size_t)s0 * F + lane * 4);
                ushort4 v1 = *(const ushort4*)(hfeat + (size_t)s1 * F + lane * 4);
                ushort4 v2 = *(const ushort4*)(hfeat + (size_t)s2 * F + lane * 4);
                ushort4 v3 = *(const ushort4*)(hfeat + (size_t)s3 * F + lane * 4);
                float w0 = __expf(lrelu(as0 + adstf)); float w1 = __expf(lrelu(as1 + adstf));
                float w2 = __expf(lrelu(as2 + adstf)); float w3 = __expf(lrelu(as3 + adstf));
                den += (w0 + w1) + (w2 + w3);
                acc[0] = fmaf(w0, bf2f(v0.x), acc[0]); acc[1] = fmaf(w0, bf2f(v0.y), acc[1]);
                acc[2] = fmaf(w0, bf2f(v0.z), acc[2]); acc[3] = fmaf(w0, bf2f(v0.w), acc[3]);
                acc[0] = fmaf(w1, bf2f(v1.x), acc[0]); acc[1] = fmaf(w1, bf2f(v1.y), acc[1]);
                acc[2] = fmaf(w1, bf2f(v1.z), acc[2]); acc[3] = fmaf(w1, bf2f(v1.w), acc[3]);
                acc[0] = fmaf(w2, bf2f(v2.x), acc[0]); acc[1] = fmaf(w2, bf2f(v2.y), acc[1]);
                acc[2] = fmaf(w2, bf2f(v2.z), acc[2]); acc[3] = fmaf(w2, bf2f(v2.w), acc[3]);
                acc[0] = fmaf(w3, bf2f(v3.x), acc[0]); acc[1] = fmaf(w3, bf2f(v3.y), acc[1]);
                acc[2] = fmaf(w3, bf2f(v3.z), acc[2]); acc[3] = fmaf(w3, bf2f(v3.w), acc[3]);
            } else {
                ushort2 v0 = *(const ushort2*)(hfeat + (size_t)s0 * F + lane * 2);
                ushort2 v1 = *(const ushort2*)(hfeat + (size_t)s1 * F + lane * 2);
                ushort2 v2 = *(const ushort2*)(hfeat + (size_t)s2 * F + lane * 2);
                ushort2 v3 = *(const ushort2*)(hfeat + (size_t)s3 * F + lane * 2);
                float w0 = __expf(lrelu(as0 + adstf)); float w1 = __expf(lrelu(as1 + adstf));
                float w2 = __expf(lrelu(as2 + adstf)); float w3 = __expf(lrelu(as3 + adstf));
                den += (w0 + w1) + (w2 + w3);
                acc[0] = fmaf(w0, bf2f(v0.x), acc[0]); acc[1] = fmaf(w0, bf2f(v0.y), acc[1]);
                acc[0] = fmaf(w1, bf2f(v1.x), acc[0]); acc[1] = fmaf(w1, bf2f(v1.y), acc[1]);
                acc[0] = fmaf(w2, bf2f(v2.x), acc[0]); acc[1] = fmaf(w2, bf2f(v2.y), acc[1]);
                acc[0] = fmaf(w3, bf2f(v3.x), acc[0]); acc[1] = fmaf(w3, bf2f(v3.y), acc[1]);
            }
        }
        for (; e < cnt; e++) {
            int s = __shfl(myid, e);
            float w = __expf(lrelu(a_src[s * 8 + hf] + adstf));
            den += w;
            if constexpr (!LAYER2) {
                ushort4 hv = *(const ushort4*)(hfeat + (size_t)s * F + lane * 4);
                acc[0] = fmaf(w, bf2f(hv.x), acc[0]); acc[1] = fmaf(w, bf2f(hv.y), acc[1]);
                acc[2] = fmaf(w, bf2f(hv.z), acc[2]); acc[3] = fmaf(w, bf2f(hv.w), acc[3]);
            } else {
                ushort2 hv = *(const ushort2*)(hfeat + (size_t)s * F + lane * 2);
                acc[0] = fmaf(w, bf2f(hv.x), acc[0]); acc[1] = fmaf(w, bf2f(hv.y), acc[1]);
            }
        }
    }

    const float inv = 1.f / (den + 1e-16f);

    if constexpr (!LAYER2) {
        // elu(acc/den + bias) -> bf16 x2
        ushort4 o;
        float v0 = acc[0] * inv + bias[lane * 4 + 0];
        float v1 = acc[1] * inv + bias[lane * 4 + 1];
        float v2 = acc[2] * inv + bias[lane * 4 + 2];
        float v3 = acc[3] * inv + bias[lane * 4 + 3];
        o.x = f2bf(v0 > 0.f ? v0 : __expf(v0) - 1.f);
        o.y = f2bf(v1 > 0.f ? v1 : __expf(v1) - 1.f);
        o.z = f2bf(v2 > 0.f ? v2 : __expf(v2) - 1.f);
        o.w = f2bf(v3 > 0.f ? v3 : __expf(v3) - 1.f);
        *(ushort4*)((unsigned short*)outp + (size_t)n * F + lane * 4) = o;
    } else {
        // normalize, then head-mean via butterfly over head-lanes
        float a0 = acc[0] * inv, a1 = acc[1] * inv;
#pragma unroll
        for (int off = 8; off <= 32; off <<= 1) {
            a0 += __shfl_xor(a0, off);
            a1 += __shfl_xor(a1, off);
        }
        if (lane < 8) {
            float2 o;
            o.x = a0 * 0.125f + bias[lane * 2 + 0];
            o.y = a1 * 0.125f + bias[lane * 2 + 1];
            *(float2*)((float*)outp + (size_t)n * 16 + lane * 2) = o;
        }
    }
}

// ---- host ---------------------------------------------------------------

extern "C" void kernel_launch(void* const* d_in, const int* in_sizes, int n_in,
                              void* d_out, int out_size, void* d_ws, size_t ws_size,
                              hipStream_t stream) {
    const float* x        = (const float*)d_in[0];
    const int*   ei       = (const int*)d_in[1];
    const float* W1       = (const float*)d_in[2];
    const float* att_src1 = (const float*)d_in[3];
    const float* att_dst1 = (const float*)d_in[4];
    const float* bias1    = (const float*)d_in[5];
    const float* W2       = (const float*)d_in[6];
    const float* att_src2 = (const float*)d_in[7];
    const float* att_dst2 = (const float*)d_in[8];
    const float* bias2    = (const float*)d_in[9];
    float* out = (float*)d_out;

    char* ws = (char*)d_ws;
    unsigned short* h1  = (unsigned short*)(ws);                       // bf16 [N,256]
    unsigned short* h2  = (unsigned short*)(ws);                       // bf16 [N,128] overlays
    unsigned short* xb  = (unsigned short*)(ws + 32ull * 1024 * 1024); // bf16 [N,256]
    unsigned short* x2b = (unsigned short*)(ws + 64ull * 1024 * 1024); // bf16 [N,256]
    unsigned short* W1T = (unsigned short*)(ws + 96ull * 1024 * 1024); // bf16 [256,256]
    unsigned short* W2T = W1T + 65536;                                 // bf16 [128,256]
    char* aux = ws + 97ull * 1024 * 1024;
    float*          a_src     = (float*)(aux);
    float*          a_dst     = (float*)(aux + 1600000);
    int*            row_start = (int*)  (aux + 3200000);
    int*            cnt       = (int*)  (aux + 3400064);
    unsigned short* csr       = (unsigned short*)(aux + 3600128);

    const int E_BLOCKS  = (EP + 255) / 256;
    const int NH_BLOCKS = (N_NODES * HEADS + 255) / 256;
    const int MT = (N_NODES + 63) / 64;            // 782
    const int AGG_BLOCKS = (N_NODES + 3) / 4;
    const int PREP_BLOCKS = (PREP_X4 + 65536 + 32768 + 255) / 256;

    // ---- prep + CSR build ----
    hipMemsetAsync(cnt, 0, N_NODES * sizeof(int), stream);
    prep_kernel<<<PREP_BLOCKS, 256, 0, stream>>>(x, W1, W2, xb, W1T, W2T);
    hist_kernel<<<E_BLOCKS, 256, 0, stream>>>(ei, cnt);
    scan_excl<<<1, SCAN_T, 0, stream>>>(cnt, row_start);
    fill_kernel<<<E_BLOCKS, 256, 0, stream>>>(ei, cnt, csr);

    // ---- layer 1 ----
    gemm_bf16<256><<<dim3(MT, 4), 256, 0, stream>>>(xb, W1T, h1);
    att_init<32><<<NH_BLOCKS, 256, 0, stream>>>(h1, att_src1, att_dst1, a_src, a_dst);
    gat_agg_fused<32, false><<<AGG_BLOCKS, 256, 0, stream>>>(row_start, csr, h1, a_src, a_dst, bias1, x2b);

    // ---- layer 2 ----
    gemm_bf16<128><<<dim3(MT, 2), 256, 0, stream>>>(x2b, W2T, h2);
    att_init<16><<<NH_BLOCKS, 256, 0, stream>>>(h2, att_src2, att_dst2, a_src, a_dst);
    gat_agg_fused<16, true><<<AGG_BLOCKS, 256, 0, stream>>>(row_start, csr, h2, a_src, a_dst, bias2, out);
}

// Round 7
// 350.688 us; speedup vs baseline: 11.5037x; 1.1143x over previous
//
#include <hip/hip_runtime.h>

#define N_NODES 50000
#define N_EDGES 800000
#define EP (N_EDGES + N_NODES)   /* 850000 edges incl. self loops */
#define HEADS 8
#define NEG 0.2f

typedef __attribute__((ext_vector_type(8))) short bf16x8;
typedef __attribute__((ext_vector_type(8))) unsigned short u16x8;
typedef __attribute__((ext_vector_type(4))) float f32x4;

// ---- bf16 helpers (storage compression; math stays fp32) ----------------

__device__ __forceinline__ float bf2f(unsigned short u) {
    return __uint_as_float(((unsigned)u) << 16);
}
__device__ __forceinline__ unsigned short f2bf(float f) {
    unsigned u = __float_as_uint(f);
    return (unsigned short)((u + 0x7FFFu + ((u >> 16) & 1u)) >> 16);  // RNE
}

__device__ __forceinline__ void get_edge(const int* __restrict__ ei, int e, int& s, int& d) {
    if (e < N_EDGES) { s = ei[e]; d = ei[N_EDGES + e]; }
    else             { s = d = e - N_EDGES; }           // self loop
}

__device__ __forceinline__ float lrelu(float v) { return v > 0.f ? v : NEG * v; }

// ---- prep: x -> bf16, W1/W2 -> bf16 transposed [n][k] -------------------

#define PREP_X4 3200000                       /* 12.8M floats / 4 */
__global__ void prep_kernel(const float* __restrict__ x, const float* __restrict__ W1,
                            const float* __restrict__ W2, unsigned short* __restrict__ xb,
                            unsigned short* __restrict__ W1T, unsigned short* __restrict__ W2T) {
    int t = blockIdx.x * 256 + threadIdx.x;
    if (t < PREP_X4) {
        float4 v = ((const float4*)x)[t];
        ushort4 o;
        o.x = f2bf(v.x); o.y = f2bf(v.y); o.z = f2bf(v.z); o.w = f2bf(v.w);
        ((ushort4*)xb)[t] = o;
    } else if (t < PREP_X4 + 65536) {
        int u = t - PREP_X4; int k = u >> 8, n = u & 255;
        W1T[n * 256 + k] = f2bf(W1[k * 256 + n]);
    } else if (t < PREP_X4 + 65536 + 32768) {
        int u = t - (PREP_X4 + 65536); int k = u >> 7, n = u & 127;
        W2T[n * 256 + k] = f2bf(W2[k * 128 + n]);
    }
}

// ---- CSR build: histogram -> 3-phase parallel scan -> fill --------------

__global__ void hist_kernel(const int* __restrict__ ei, int* __restrict__ cnt) {
    int e = blockIdx.x * 256 + threadIdx.x;
    if (e >= EP) return;
    int s, d; get_edge(ei, e, s, d);
    atomicAdd(&cnt[d], 1);
}

#define SCAN_BLOCKS 196   /* 196*256 = 50176 >= N_NODES */

__global__ __launch_bounds__(256) void scan_p1(const int* __restrict__ cnt,
                                               int* __restrict__ incl, int* __restrict__ bsum) {
    __shared__ int wsum[4];
    const int tid = threadIdx.x, lane = tid & 63, wid = tid >> 6;
    const int idx = blockIdx.x * 256 + tid;
    int v = (idx < N_NODES) ? cnt[idx] : 0;
#pragma unroll
    for (int off = 1; off < 64; off <<= 1) {
        int t = __shfl_up(v, off);
        if (lane >= off) v += t;
    }
    if (lane == 63) wsum[wid] = v;
    __syncthreads();
    int add = 0;
#pragma unroll
    for (int w = 0; w < 4; w++) add += (w < wid) ? wsum[w] : 0;
    incl[idx] = v + add;                         // incl buffer padded to 50176
    if (tid == 255) bsum[blockIdx.x] = v + add;
}

__global__ __launch_bounds__(256) void scan_p2(const int* __restrict__ bsum,
                                               int* __restrict__ bex) {
    __shared__ int wsum[4];
    const int tid = threadIdx.x, lane = tid & 63, wid = tid >> 6;
    int v0 = (tid < SCAN_BLOCKS) ? bsum[tid] : 0;
    int v = v0;
#pragma unroll
    for (int off = 1; off < 64; off <<= 1) {
        int t = __shfl_up(v, off);
        if (lane >= off) v += t;
    }
    if (lane == 63) wsum[wid] = v;
    __syncthreads();
    int add = 0;
#pragma unroll
    for (int w = 0; w < 4; w++) add += (w < wid) ? wsum[w] : 0;
    if (tid < SCAN_BLOCKS) bex[tid] = v + add - v0;
}

__global__ __launch_bounds__(256) void scan_p3(const int* __restrict__ incl,
                                               const int* __restrict__ bex,
                                               int* __restrict__ cnt_cursor,
                                               int* __restrict__ row_start) {
    const int idx = blockIdx.x * 256 + threadIdx.x;
    if (idx == 0) row_start[N_NODES] = EP;
    if (idx >= N_NODES) return;
    int ex = bex[blockIdx.x] + incl[idx] - cnt_cursor[idx];
    row_start[idx] = ex;
    cnt_cursor[idx] = ex;
}

__global__ void fill_kernel(const int* __restrict__ ei, int* __restrict__ cursor,
                            unsigned short* __restrict__ csr) {
    int e = blockIdx.x * 256 + threadIdx.x;
    if (e >= EP) return;
    int s, d; get_edge(ei, e, s, d);
    int pos = atomicAdd(&cursor[d], 1);
    csr[pos] = (unsigned short)s;
}

// ---- MFMA GEMM, A read ONCE (BM=64 x full-N) + fused attention epilogue -
// 4 waves; wave w covers n in [w*WN, w*WN+WN), WN = NC/4; heads/wave = 2.
// XOR-swizzled LDS (chunk c of row r at c^(r&7)): conflict-free b128 reads.
// Epilogue computes a_src/a_dst from fp32 acc via butterfly over col lanes.

template<int NC, int C>
__global__ __launch_bounds__(256) void gemm_fused(const unsigned short* __restrict__ A,
        const unsigned short* __restrict__ WT,
        const float* __restrict__ att_s, const float* __restrict__ att_d,
        unsigned short* __restrict__ outh,
        float* __restrict__ a_src, float* __restrict__ a_dst) {
    constexpr int WN  = NC / 4;        // 64 or 32
    constexpr int NT  = WN / 16;       // ni tiles per wave: 4 or 2
    constexpr int TPH = C / 16;        // ni tiles per head: 2 or 1
    constexpr int BJ  = NC / 32;       // B-stage chunks per thread: 8 or 4
    __shared__ unsigned short As[64 * 64];
    __shared__ unsigned short Bs[NC * 64];
    const int m0 = blockIdx.x * 64;
    const int tid  = threadIdx.x;
    const int wave = tid >> 6, lane = tid & 63;
    const int col = lane & 15, quad = lane >> 4;
    const int ar = tid >> 2;           // A stager: row 0..63
    const int ac = tid & 3;            // A stager: chunk phase

    f32x4 acc[4][NT] = {};

    for (int k0 = 0; k0 < 256; k0 += 64) {
        u16x8 av[2];
#pragma unroll
        for (int j = 0; j < 2; j++)
            av[j] = *(const u16x8*)(A + (size_t)(m0 + ar) * 256 + k0 + (ac + j * 4) * 8);
        u16x8 bv[BJ];
#pragma unroll
        for (int j = 0; j < BJ; j++) {
            int idx = j * 256 + tid, row = idx >> 3, ch = idx & 7;
            bv[j] = *(const u16x8*)(WT + (size_t)row * 256 + k0 + ch * 8);
        }
        __syncthreads();                         // prior mfma reads done
#pragma unroll
        for (int j = 0; j < 2; j++) {
            int ch = ac + j * 4;
            *(u16x8*)&As[ar * 64 + (ch ^ (ar & 7)) * 8] = av[j];
        }
#pragma unroll
        for (int j = 0; j < BJ; j++) {
            int idx = j * 256 + tid, row = idx >> 3, ch = idx & 7;
            *(u16x8*)&Bs[row * 64 + (ch ^ (row & 7)) * 8] = bv[j];
        }
        __syncthreads();
#pragma unroll
        for (int ks = 0; ks < 64; ks += 32) {
            bf16x8 af[4], bfm[NT];
#pragma unroll
            for (int mi = 0; mi < 4; mi++) {
                int r = mi * 16 + col, c = (ks >> 3) + quad;
                af[mi] = *(const bf16x8*)&As[r * 64 + (c ^ (r & 7)) * 8];
            }
#pragma unroll
            for (int ni = 0; ni < NT; ni++) {
                int r = wave * WN + ni * 16 + col, c = (ks >> 3) + quad;
                bfm[ni] = *(const bf16x8*)&Bs[r * 64 + (c ^ (r & 7)) * 8];
            }
#pragma unroll
            for (int mi = 0; mi < 4; mi++)
#pragma unroll
                for (int ni = 0; ni < NT; ni++)
                    acc[mi][ni] = __builtin_amdgcn_mfma_f32_16x16x32_bf16(
                        af[mi], bfm[ni], acc[mi][ni], 0, 0, 0);
        }
    }

    // ---- write h (C/D: col = lane&15 -> n, quad*4+r -> m) ----
#pragma unroll
    for (int mi = 0; mi < 4; mi++)
#pragma unroll
        for (int ni = 0; ni < NT; ni++)
#pragma unroll
            for (int r = 0; r < 4; r++) {
                int m = m0 + mi * 16 + quad * 4 + r;
                if (m < N_NODES)
                    outh[(size_t)m * NC + wave * WN + ni * 16 + col] = f2bf(acc[mi][ni][r]);
            }

    // ---- fused attention-coefficient epilogue ----
    // feature n == hh*C + cl, so att_s[n] is this lane's coefficient.
    float asv[NT], adv[NT];
#pragma unroll
    for (int ni = 0; ni < NT; ni++) {
        int n = wave * WN + ni * 16 + col;
        asv[ni] = att_s[n];
        adv[ni] = att_d[n];
    }
#pragma unroll
    for (int mi = 0; mi < 4; mi++)
#pragma unroll
        for (int r = 0; r < 4; r++) {
#pragma unroll
            for (int hl = 0; hl < 2; hl++) {     // heads per wave == 2
                float s = 0.f, d = 0.f;
#pragma unroll
                for (int t = 0; t < TPH; t++) {
                    int ni = hl * TPH + t;
                    s = fmaf(acc[mi][ni][r], asv[ni], s);
                    d = fmaf(acc[mi][ni][r], adv[ni], d);
                }
#pragma unroll
                for (int off = 1; off < 16; off <<= 1) {
                    s += __shfl_xor(s, off);
                    d += __shfl_xor(d, off);
                }
                if (col == 0) {
                    int m = m0 + mi * 16 + quad * 4 + r;
                    if (m < N_NODES) {
                        int hh = wave * 2 + hl;
                        a_src[m * 8 + hh] = s;
                        a_dst[m * 8 + hh] = d;
                    }
                }
            }
        }
}

// ---- fused single-pass softmax+aggregate: ONE WAVE per node -------------
// No max-subtraction (|e| small analytically -> exp safe in fp32).
// Edge ids preloaded per 64-chunk, broadcast via __shfl; gathers batched x8.

template<int C, bool LAYER2>
__global__ __launch_bounds__(256) void gat_agg_fused(const int* __restrict__ row_start,
        const unsigned short* __restrict__ csr,
        const unsigned short* __restrict__ hfeat, const float* __restrict__ a_src,
        const float* __restrict__ a_dst, const float* __restrict__ bias,
        void* __restrict__ outp) {
    constexpr int F  = 8 * C;          // 256 or 128
    constexpr int VF = F / 64;         // feats per lane: 4 or 2
    const int n    = blockIdx.x * 4 + (threadIdx.x >> 6);
    const int lane = threadIdx.x & 63;
    if (n >= N_NODES) return;

    const int rs  = row_start[n];
    const int deg = row_start[n + 1] - rs;     // >= 1 (self loop)
    const int hf  = lane >> 3;                 // this lane's head
    const float adstf = a_dst[n * 8 + hf];

    float acc[VF] = {};
    float den = 0.f;

    for (int c0 = 0; c0 < deg; c0 += 64) {
        const int cnt = min(64, deg - c0);
        int myid = (lane < cnt) ? (int)csr[rs + c0 + lane] : 0;
        int e = 0;
        for (; e + 8 <= cnt; e += 8) {
            int ss[8];
#pragma unroll
            for (int j = 0; j < 8; j++) ss[j] = __shfl(myid, e + j);
            float as[8];
#pragma unroll
            for (int j = 0; j < 8; j++) as[j] = a_src[ss[j] * 8 + hf];
            if constexpr (!LAYER2) {
                ushort4 v[8];
#pragma unroll
                for (int j = 0; j < 8; j++)
                    v[j] = *(const ushort4*)(hfeat + (size_t)ss[j] * F + lane * 4);
#pragma unroll
                for (int j = 0; j < 8; j++) {
                    float w = __expf(lrelu(as[j] + adstf));
                    den += w;
                    acc[0] = fmaf(w, bf2f(v[j].x), acc[0]);
                    acc[1] = fmaf(w, bf2f(v[j].y), acc[1]);
                    acc[2] = fmaf(w, bf2f(v[j].z), acc[2]);
                    acc[3] = fmaf(w, bf2f(v[j].w), acc[3]);
                }
            } else {
                ushort2 v[8];
#pragma unroll
                for (int j = 0; j < 8; j++)
                    v[j] = *(const ushort2*)(hfeat + (size_t)ss[j] * F + lane * 2);
#pragma unroll
                for (int j = 0; j < 8; j++) {
                    float w = __expf(lrelu(as[j] + adstf));
                    den += w;
                    acc[0] = fmaf(w, bf2f(v[j].x), acc[0]);
                    acc[1] = fmaf(w, bf2f(v[j].y), acc[1]);
                }
            }
        }
        for (; e < cnt; e++) {
            int s = __shfl(myid, e);
            float w = __expf(lrelu(a_src[s * 8 + hf] + adstf));
            den += w;
            if constexpr (!LAYER2) {
                ushort4 hv = *(const ushort4*)(hfeat + (size_t)s * F + lane * 4);
                acc[0] = fmaf(w, bf2f(hv.x), acc[0]); acc[1] = fmaf(w, bf2f(hv.y), acc[1]);
                acc[2] = fmaf(w, bf2f(hv.z), acc[2]); acc[3] = fmaf(w, bf2f(hv.w), acc[3]);
            } else {
                ushort2 hv = *(const ushort2*)(hfeat + (size_t)s * F + lane * 2);
                acc[0] = fmaf(w, bf2f(hv.x), acc[0]); acc[1] = fmaf(w, bf2f(hv.y), acc[1]);
            }
        }
    }

    const float inv = 1.f / (den + 1e-16f);

    if constexpr (!LAYER2) {
        ushort4 o;
        float v0 = acc[0] * inv + bias[lane * 4 + 0];
        float v1 = acc[1] * inv + bias[lane * 4 + 1];
        float v2 = acc[2] * inv + bias[lane * 4 + 2];
        float v3 = acc[3] * inv + bias[lane * 4 + 3];
        o.x = f2bf(v0 > 0.f ? v0 : __expf(v0) - 1.f);
        o.y = f2bf(v1 > 0.f ? v1 : __expf(v1) - 1.f);
        o.z = f2bf(v2 > 0.f ? v2 : __expf(v2) - 1.f);
        o.w = f2bf(v3 > 0.f ? v3 : __expf(v3) - 1.f);
        *(ushort4*)((unsigned short*)outp + (size_t)n * F + lane * 4) = o;
    } else {
        float a0 = acc[0] * inv, a1 = acc[1] * inv;
#pragma unroll
        for (int off = 8; off <= 32; off <<= 1) {
            a0 += __shfl_xor(a0, off);
            a1 += __shfl_xor(a1, off);
        }
        if (lane < 8) {
            float2 o;
            o.x = a0 * 0.125f + bias[lane * 2 + 0];
            o.y = a1 * 0.125f + bias[lane * 2 + 1];
            *(float2*)((float*)outp + (size_t)n * 16 + lane * 2) = o;
        }
    }
}

// ---- host ---------------------------------------------------------------

extern "C" void kernel_launch(void* const* d_in, const int* in_sizes, int n_in,
                              void* d_out, int out_size, void* d_ws, size_t ws_size,
                              hipStream_t stream) {
    const float* x        = (const float*)d_in[0];
    const int*   ei       = (const int*)d_in[1];
    const float* W1       = (const float*)d_in[2];
    const float* att_src1 = (const float*)d_in[3];
    const float* att_dst1 = (const float*)d_in[4];
    const float* bias1    = (const float*)d_in[5];
    const float* W2       = (const float*)d_in[6];
    const float* att_src2 = (const float*)d_in[7];
    const float* att_dst2 = (const float*)d_in[8];
    const float* bias2    = (const float*)d_in[9];
    float* out = (float*)d_out;

    char* ws = (char*)d_ws;
    unsigned short* h1  = (unsigned short*)(ws);                       // bf16 [N,256]
    unsigned short* h2  = (unsigned short*)(ws);                       // bf16 [N,128] overlays
    unsigned short* xb  = (unsigned short*)(ws + 32ull * 1024 * 1024); // bf16 [N,256]
    unsigned short* x2b = (unsigned short*)(ws + 64ull * 1024 * 1024); // bf16 [N,256]
    unsigned short* W1T = (unsigned short*)(ws + 96ull * 1024 * 1024); // bf16 [256,256]
    unsigned short* W2T = W1T + 65536;                                 // bf16 [128,256]
    char* aux = ws + 97ull * 1024 * 1024;
    float*          a_src     = (float*)(aux);                         // [N,8]
    float*          a_dst     = (float*)(aux + 1600000);               // [N,8]
    int*            row_start = (int*)  (aux + 3200000);               // [N+1]
    int*            cnt       = (int*)  (aux + 3400064);               // [N] -> cursor
    unsigned short* csr       = (unsigned short*)(aux + 3600128);      // [EP]
    int*            incl      = (int*)  (aux + 5300128);               // [50176]
    int*            bsum      = (int*)  (aux + 5500832);               // [196]
    int*            bex       = (int*)  (aux + 5501632);               // [196]

    const int E_BLOCKS  = (EP + 255) / 256;
    const int MT = (N_NODES + 63) / 64;            // 782
    const int AGG_BLOCKS = (N_NODES + 3) / 4;
    const int PREP_BLOCKS = (PREP_X4 + 65536 + 32768 + 255) / 256;

    // ---- prep + CSR build ----
    hipMemsetAsync(cnt, 0, N_NODES * sizeof(int), stream);
    prep_kernel<<<PREP_BLOCKS, 256, 0, stream>>>(x, W1, W2, xb, W1T, W2T);
    hist_kernel<<<E_BLOCKS, 256, 0, stream>>>(ei, cnt);
    scan_p1<<<SCAN_BLOCKS, 256, 0, stream>>>(cnt, incl, bsum);
    scan_p2<<<1, 256, 0, stream>>>(bsum, bex);
    scan_p3<<<SCAN_BLOCKS, 256, 0, stream>>>(incl, bex, cnt, row_start);
    fill_kernel<<<E_BLOCKS, 256, 0, stream>>>(ei, cnt, csr);

    // ---- layer 1 ----
    gemm_fused<256, 32><<<MT, 256, 0, stream>>>(xb, W1T, att_src1, att_dst1, h1, a_src, a_dst);
    gat_agg_fused<32, false><<<AGG_BLOCKS, 256, 0, stream>>>(row_start, csr, h1, a_src, a_dst, bias1, x2b);

    // ---- layer 2 ----
    gemm_fused<128, 16><<<MT, 256, 0, stream>>>(x2b, W2T, att_src2, att_dst2, h2, a_src, a_dst);
    gat_agg_fused<16, true><<<AGG_BLOCKS, 256, 0, stream>>>(row_start, csr, h2, a_src, a_dst, bias2, out);
}

// Round 8
// 341.727 us; speedup vs baseline: 11.8053x; 1.0262x over previous
//
#include <hip/hip_runtime.h>

#define N_NODES 50000
#define N_EDGES 800000
#define EP (N_EDGES + N_NODES)   /* 850000 edges incl. self loops */
#define HEADS 8
#define NEG 0.2f

typedef __attribute__((ext_vector_type(8))) short bf16x8;
typedef __attribute__((ext_vector_type(8))) unsigned short u16x8;
typedef __attribute__((ext_vector_type(4))) float f32x4;

// ---- bf16 helpers (storage compression; math stays fp32) ----------------

__device__ __forceinline__ float bf2f(unsigned short u) {
    return __uint_as_float(((unsigned)u) << 16);
}
__device__ __forceinline__ unsigned short f2bf(float f) {
    unsigned u = __float_as_uint(f);
    return (unsigned short)((u + 0x7FFFu + ((u >> 16) & 1u)) >> 16);  // RNE
}

__device__ __forceinline__ void get_edge(const int* __restrict__ ei, int e, int& s, int& d) {
    if (e < N_EDGES) { s = ei[e]; d = ei[N_EDGES + e]; }
    else             { s = d = e - N_EDGES; }           // self loop
}

__device__ __forceinline__ float lrelu(float v) { return v > 0.f ? v : NEG * v; }

// ---- hist + W-transpose (fused, independent work ranges) ----------------

#define E_BLOCKS ((EP + 255) / 256)        /* 3321 */
#define W_ITEMS  (65536 + 32768)
#define W_BLOCKS ((W_ITEMS + 255) / 256)   /* 384 */

__global__ void hist_prep(const int* __restrict__ ei, int* __restrict__ cnt,
                          const float* __restrict__ W1, const float* __restrict__ W2,
                          unsigned short* __restrict__ W1T, unsigned short* __restrict__ W2T) {
    const int b = blockIdx.x;
    if (b < E_BLOCKS) {
        int e = b * 256 + threadIdx.x;
        if (e >= EP) return;
        int s, d; get_edge(ei, e, s, d);
        atomicAdd(&cnt[d], 1);
    } else {
        int t = (b - E_BLOCKS) * 256 + threadIdx.x;
        if (t < 65536) {
            int k = t >> 8, n = t & 255;
            W1T[n * 256 + k] = f2bf(W1[k * 256 + n]);
        } else if (t < W_ITEMS) {
            int u = t - 65536; int k = u >> 7, n = u & 127;
            W2T[n * 256 + k] = f2bf(W2[k * 128 + n]);
        }
    }
}

// ---- 3-phase parallel exclusive scan ------------------------------------

#define SCAN_BLOCKS 196   /* 196*256 = 50176 >= N_NODES */

__global__ __launch_bounds__(256) void scan_p1(const int* __restrict__ cnt,
                                               int* __restrict__ incl, int* __restrict__ bsum) {
    __shared__ int wsum[4];
    const int tid = threadIdx.x, lane = tid & 63, wid = tid >> 6;
    const int idx = blockIdx.x * 256 + tid;
    int v = (idx < N_NODES) ? cnt[idx] : 0;
#pragma unroll
    for (int off = 1; off < 64; off <<= 1) {
        int t = __shfl_up(v, off);
        if (lane >= off) v += t;
    }
    if (lane == 63) wsum[wid] = v;
    __syncthreads();
    int add = 0;
#pragma unroll
    for (int w = 0; w < 4; w++) add += (w < wid) ? wsum[w] : 0;
    incl[idx] = v + add;
    if (tid == 255) bsum[blockIdx.x] = v + add;
}

__global__ __launch_bounds__(256) void scan_p2(const int* __restrict__ bsum,
                                               int* __restrict__ bex) {
    __shared__ int wsum[4];
    const int tid = threadIdx.x, lane = tid & 63, wid = tid >> 6;
    int v0 = (tid < SCAN_BLOCKS) ? bsum[tid] : 0;
    int v = v0;
#pragma unroll
    for (int off = 1; off < 64; off <<= 1) {
        int t = __shfl_up(v, off);
        if (lane >= off) v += t;
    }
    if (lane == 63) wsum[wid] = v;
    __syncthreads();
    int add = 0;
#pragma unroll
    for (int w = 0; w < 4; w++) add += (w < wid) ? wsum[w] : 0;
    if (tid < SCAN_BLOCKS) bex[tid] = v + add - v0;
}

__global__ __launch_bounds__(256) void scan_p3(const int* __restrict__ incl,
                                               const int* __restrict__ bex,
                                               int* __restrict__ cnt_cursor,
                                               int* __restrict__ row_start) {
    const int idx = blockIdx.x * 256 + threadIdx.x;
    if (idx == 0) row_start[N_NODES] = EP;
    if (idx >= N_NODES) return;
    int ex = bex[blockIdx.x] + incl[idx] - cnt_cursor[idx];
    row_start[idx] = ex;
    cnt_cursor[idx] = ex;
}

__global__ void fill_kernel(const int* __restrict__ ei, int* __restrict__ cursor,
                            unsigned short* __restrict__ csr) {
    int e = blockIdx.x * 256 + threadIdx.x;
    if (e >= EP) return;
    int s, d; get_edge(ei, e, s, d);
    int pos = atomicAdd(&cursor[d], 1);
    csr[pos] = (unsigned short)s;
}

// ---- MFMA GEMM, A read ONCE (BM=64 x full-N) + fused attention epilogue -
// 4 waves; wave w covers n in [w*WN, w*WN+WN); AF32: A is fp32, converted
// during staging (layer 1 reads x directly — no xb round-trip).
// XOR-swizzled LDS: conflict-free ds_read_b128. Epilogue computes
// a_src/a_dst from the fp32 accumulators via 16-lane butterflies.

template<int NC, int C, bool AF32>
__global__ __launch_bounds__(256) void gemm_fused(const void* __restrict__ Aptr,
        const unsigned short* __restrict__ WT,
        const float* __restrict__ att_s, const float* __restrict__ att_d,
        unsigned short* __restrict__ outh,
        float* __restrict__ a_src, float* __restrict__ a_dst) {
    constexpr int WN  = NC / 4;
    constexpr int NT  = WN / 16;
    constexpr int TPH = C / 16;
    constexpr int BJ  = NC / 32;
    __shared__ unsigned short As[64 * 64];
    __shared__ unsigned short Bs[NC * 64];
    const int m0 = blockIdx.x * 64;
    const int tid  = threadIdx.x;
    const int wave = tid >> 6, lane = tid & 63;
    const int col = lane & 15, quad = lane >> 4;
    const int ar = tid >> 2;
    const int ac = tid & 3;
    const int arow = min(m0 + ar, N_NODES - 1);   // guard input read

    f32x4 acc[4][NT] = {};

    for (int k0 = 0; k0 < 256; k0 += 64) {
        u16x8 av[2];
        if constexpr (AF32) {
            const float* Af = (const float*)Aptr;
#pragma unroll
            for (int j = 0; j < 2; j++) {
                const float* p = Af + (size_t)arow * 256 + k0 + (ac + j * 4) * 8;
                float4 f0 = *(const float4*)p;
                float4 f1 = *(const float4*)(p + 4);
                u16x8 v;
                v[0] = f2bf(f0.x); v[1] = f2bf(f0.y); v[2] = f2bf(f0.z); v[3] = f2bf(f0.w);
                v[4] = f2bf(f1.x); v[5] = f2bf(f1.y); v[6] = f2bf(f1.z); v[7] = f2bf(f1.w);
                av[j] = v;
            }
        } else {
            const unsigned short* Ab = (const unsigned short*)Aptr;
#pragma unroll
            for (int j = 0; j < 2; j++)
                av[j] = *(const u16x8*)(Ab + (size_t)arow * 256 + k0 + (ac + j * 4) * 8);
        }
        u16x8 bv[BJ];
#pragma unroll
        for (int j = 0; j < BJ; j++) {
            int idx = j * 256 + tid, row = idx >> 3, ch = idx & 7;
            bv[j] = *(const u16x8*)(WT + (size_t)row * 256 + k0 + ch * 8);
        }
        __syncthreads();
#pragma unroll
        for (int j = 0; j < 2; j++) {
            int ch = ac + j * 4;
            *(u16x8*)&As[ar * 64 + (ch ^ (ar & 7)) * 8] = av[j];
        }
#pragma unroll
        for (int j = 0; j < BJ; j++) {
            int idx = j * 256 + tid, row = idx >> 3, ch = idx & 7;
            *(u16x8*)&Bs[row * 64 + (ch ^ (row & 7)) * 8] = bv[j];
        }
        __syncthreads();
#pragma unroll
        for (int ks = 0; ks < 64; ks += 32) {
            bf16x8 af[4], bfm[NT];
#pragma unroll
            for (int mi = 0; mi < 4; mi++) {
                int r = mi * 16 + col, c = (ks >> 3) + quad;
                af[mi] = *(const bf16x8*)&As[r * 64 + (c ^ (r & 7)) * 8];
            }
#pragma unroll
            for (int ni = 0; ni < NT; ni++) {
                int r = wave * WN + ni * 16 + col, c = (ks >> 3) + quad;
                bfm[ni] = *(const bf16x8*)&Bs[r * 64 + (c ^ (r & 7)) * 8];
            }
#pragma unroll
            for (int mi = 0; mi < 4; mi++)
#pragma unroll
                for (int ni = 0; ni < NT; ni++)
                    acc[mi][ni] = __builtin_amdgcn_mfma_f32_16x16x32_bf16(
                        af[mi], bfm[ni], acc[mi][ni], 0, 0, 0);
        }
    }

#pragma unroll
    for (int mi = 0; mi < 4; mi++)
#pragma unroll
        for (int ni = 0; ni < NT; ni++)
#pragma unroll
            for (int r = 0; r < 4; r++) {
                int m = m0 + mi * 16 + quad * 4 + r;
                if (m < N_NODES)
                    outh[(size_t)m * NC + wave * WN + ni * 16 + col] = f2bf(acc[mi][ni][r]);
            }

    float asv[NT], adv[NT];
#pragma unroll
    for (int ni = 0; ni < NT; ni++) {
        int n = wave * WN + ni * 16 + col;
        asv[ni] = att_s[n];
        adv[ni] = att_d[n];
    }
#pragma unroll
    for (int mi = 0; mi < 4; mi++)
#pragma unroll
        for (int r = 0; r < 4; r++) {
#pragma unroll
            for (int hl = 0; hl < 2; hl++) {
                float s = 0.f, d = 0.f;
#pragma unroll
                for (int t = 0; t < TPH; t++) {
                    int ni = hl * TPH + t;
                    s = fmaf(acc[mi][ni][r], asv[ni], s);
                    d = fmaf(acc[mi][ni][r], adv[ni], d);
                }
#pragma unroll
                for (int off = 1; off < 16; off <<= 1) {
                    s += __shfl_xor(s, off);
                    d += __shfl_xor(d, off);
                }
                if (col == 0) {
                    int m = m0 + mi * 16 + quad * 4 + r;
                    if (m < N_NODES) {
                        int hh = wave * 2 + hl;
                        a_src[m * 8 + hh] = s;
                        a_dst[m * 8 + hh] = d;
                    }
                }
            }
        }
}

// ---- layer-1 aggregation: ONE WAVE per node, 2 edges per iteration ------
// Half-wave p = lane>>5 handles edge parity p; lane covers feats
// [q*8, q*8+8) of head q>>2 (q = lane&31) -> 16 B dwordx4 gather per lane,
// 32 lanes x 16 B = full 512 B row. Parity partial sums combined at the
// end via shfl_xor(32). No max-subtraction (|e| small -> exp safe).

__global__ __launch_bounds__(256) void gat_agg_l1(const int* __restrict__ row_start,
        const unsigned short* __restrict__ csr,
        const unsigned short* __restrict__ hfeat, const float* __restrict__ a_src,
        const float* __restrict__ a_dst, const float* __restrict__ bias,
        unsigned short* __restrict__ outp) {
    const int n    = blockIdx.x * 4 + (threadIdx.x >> 6);
    const int lane = threadIdx.x & 63;
    if (n >= N_NODES) return;

    const int rs  = row_start[n];
    const int deg = row_start[n + 1] - rs;
    const int p   = lane >> 5;          // edge parity
    const int q   = lane & 31;          // feat group
    const int hq  = q >> 2;             // head
    const float adstf = a_dst[n * 8 + hq];

    float acc[8] = {};
    float den = 0.f;

    for (int c0 = 0; c0 < deg; c0 += 64) {
        const int cnt = min(64, deg - c0);
        int myid = (lane < cnt) ? (int)csr[rs + c0 + lane] : 0;
        int e = 0;
        for (; e + 8 <= cnt; e += 8) {          // 4 pairs = 8 edges
            int ss[4];
#pragma unroll
            for (int j = 0; j < 4; j++) ss[j] = __shfl(myid, e + j * 2 + p);
            float as[4];
#pragma unroll
            for (int j = 0; j < 4; j++) as[j] = a_src[ss[j] * 8 + hq];
            u16x8 v[4];
#pragma unroll
            for (int j = 0; j < 4; j++)
                v[j] = *(const u16x8*)(hfeat + (size_t)ss[j] * 256 + q * 8);
#pragma unroll
            for (int j = 0; j < 4; j++) {
                float w = __expf(lrelu(as[j] + adstf));
                den += w;
#pragma unroll
                for (int k = 0; k < 8; k++)
                    acc[k] = fmaf(w, bf2f(v[j][k]), acc[k]);
            }
        }
        for (; e < cnt; e += 2) {               // tail pairs
            int idx = e + p;
            bool ok = idx < cnt;
            int s = __shfl(myid, ok ? idx : cnt - 1);
            float w = ok ? __expf(lrelu(a_src[s * 8 + hq] + adstf)) : 0.f;
            den += w;
            u16x8 v = *(const u16x8*)(hfeat + (size_t)s * 256 + q * 8);
#pragma unroll
            for (int k = 0; k < 8; k++)
                acc[k] = fmaf(w, bf2f(v[k]), acc[k]);
        }
    }

    // combine parities
    den += __shfl_xor(den, 32);
#pragma unroll
    for (int k = 0; k < 8; k++) acc[k] += __shfl_xor(acc[k], 32);

    if (p == 0) {
        const float inv = 1.f / (den + 1e-16f);
        float4 b0 = *(const float4*)(bias + q * 8);
        float4 b1 = *(const float4*)(bias + q * 8 + 4);
        float bb[8] = {b0.x, b0.y, b0.z, b0.w, b1.x, b1.y, b1.z, b1.w};
        u16x8 o;
#pragma unroll
        for (int k = 0; k < 8; k++) {
            float v = acc[k] * inv + bb[k];
            o[k] = f2bf(v > 0.f ? v : __expf(v) - 1.f);   // elu
        }
        *(u16x8*)(outp + (size_t)n * 256 + q * 8) = o;
    }
}

// ---- layer-2 aggregation: ONE WAVE per node (R6 structure, F=128) -------

__global__ __launch_bounds__(256) void gat_agg_l2(const int* __restrict__ row_start,
        const unsigned short* __restrict__ csr,
        const unsigned short* __restrict__ hfeat, const float* __restrict__ a_src,
        const float* __restrict__ a_dst, const float* __restrict__ bias,
        float* __restrict__ outp) {
    const int n    = blockIdx.x * 4 + (threadIdx.x >> 6);
    const int lane = threadIdx.x & 63;
    if (n >= N_NODES) return;

    const int rs  = row_start[n];
    const int deg = row_start[n + 1] - rs;
    const int hf  = lane >> 3;
    const float adstf = a_dst[n * 8 + hf];

    float acc0 = 0.f, acc1 = 0.f, den = 0.f;

    for (int c0 = 0; c0 < deg; c0 += 64) {
        const int cnt = min(64, deg - c0);
        int myid = (lane < cnt) ? (int)csr[rs + c0 + lane] : 0;
        int e = 0;
        for (; e + 8 <= cnt; e += 8) {
            int ss[8];
#pragma unroll
            for (int j = 0; j < 8; j++) ss[j] = __shfl(myid, e + j);
            float as[8];
#pragma unroll
            for (int j = 0; j < 8; j++) as[j] = a_src[ss[j] * 8 + hf];
            ushort2 v[8];
#pragma unroll
            for (int j = 0; j < 8; j++)
                v[j] = *(const ushort2*)(hfeat + (size_t)ss[j] * 128 + lane * 2);
#pragma unroll
            for (int j = 0; j < 8; j++) {
                float w = __expf(lrelu(as[j] + adstf));
                den += w;
                acc0 = fmaf(w, bf2f(v[j].x), acc0);
                acc1 = fmaf(w, bf2f(v[j].y), acc1);
            }
        }
        for (; e < cnt; e++) {
            int s = __shfl(myid, e);
            float w = __expf(lrelu(a_src[s * 8 + hf] + adstf));
            den += w;
            ushort2 hv = *(const ushort2*)(hfeat + (size_t)s * 128 + lane * 2);
            acc0 = fmaf(w, bf2f(hv.x), acc0);
            acc1 = fmaf(w, bf2f(hv.y), acc1);
        }
    }

    const float inv = 1.f / (den + 1e-16f);
    float a0 = acc0 * inv, a1 = acc1 * inv;
#pragma unroll
    for (int off = 8; off <= 32; off <<= 1) {
        a0 += __shfl_xor(a0, off);
        a1 += __shfl_xor(a1, off);
    }
    if (lane < 8) {
        float2 o;
        o.x = a0 * 0.125f + bias[lane * 2 + 0];
        o.y = a1 * 0.125f + bias[lane * 2 + 1];
        *(float2*)(outp + (size_t)n * 16 + lane * 2) = o;
    }
}

// ---- host ---------------------------------------------------------------

extern "C" void kernel_launch(void* const* d_in, const int* in_sizes, int n_in,
                              void* d_out, int out_size, void* d_ws, size_t ws_size,
                              hipStream_t stream) {
    const float* x        = (const float*)d_in[0];
    const int*   ei       = (const int*)d_in[1];
    const float* W1       = (const float*)d_in[2];
    const float* att_src1 = (const float*)d_in[3];
    const float* att_dst1 = (const float*)d_in[4];
    const float* bias1    = (const float*)d_in[5];
    const float* W2       = (const float*)d_in[6];
    const float* att_src2 = (const float*)d_in[7];
    const float* att_dst2 = (const float*)d_in[8];
    const float* bias2    = (const float*)d_in[9];
    float* out = (float*)d_out;

    char* ws = (char*)d_ws;
    unsigned short* h1  = (unsigned short*)(ws);                       // bf16 [N,256]
    unsigned short* h2  = (unsigned short*)(ws);                       // bf16 [N,128] overlays
    unsigned short* x2b = (unsigned short*)(ws + 32ull * 1024 * 1024); // bf16 [N,256]
    unsigned short* W1T = (unsigned short*)(ws + 64ull * 1024 * 1024); // bf16 [256,256]
    unsigned short* W2T = W1T + 65536;                                 // bf16 [128,256]
    char* aux = ws + 66ull * 1024 * 1024;
    float*          a_src     = (float*)(aux);                         // [N,8]
    float*          a_dst     = (float*)(aux + 1600000);               // [N,8]
    int*            row_start = (int*)  (aux + 3200000);               // [N+1]
    int*            cnt       = (int*)  (aux + 3400064);               // [N] -> cursor
    unsigned short* csr       = (unsigned short*)(aux + 3600128);      // [EP]
    int*            incl      = (int*)  (aux + 5300128);               // [50176]
    int*            bsum      = (int*)  (aux + 5500832);               // [196]
    int*            bex       = (int*)  (aux + 5501632);               // [196]

    const int MT = (N_NODES + 63) / 64;            // 782
    const int AGG_BLOCKS = (N_NODES + 3) / 4;

    // ---- CSR build + W prep ----
    hipMemsetAsync(cnt, 0, N_NODES * sizeof(int), stream);
    hist_prep<<<E_BLOCKS + W_BLOCKS, 256, 0, stream>>>(ei, cnt, W1, W2, W1T, W2T);
    scan_p1<<<SCAN_BLOCKS, 256, 0, stream>>>(cnt, incl, bsum);
    scan_p2<<<1, 256, 0, stream>>>(bsum, bex);
    scan_p3<<<SCAN_BLOCKS, 256, 0, stream>>>(incl, bex, cnt, row_start);
    fill_kernel<<<E_BLOCKS, 256, 0, stream>>>(ei, cnt, csr);

    // ---- layer 1 (GEMM reads fp32 x directly) ----
    gemm_fused<256, 32, true><<<MT, 256, 0, stream>>>(x, W1T, att_src1, att_dst1, h1, a_src, a_dst);
    gat_agg_l1<<<AGG_BLOCKS, 256, 0, stream>>>(row_start, csr, h1, a_src, a_dst, bias1, x2b);

    // ---- layer 2 ----
    gemm_fused<128, 16, false><<<MT, 256, 0, stream>>>(x2b, W2T, att_src2, att_dst2, h2, a_src, a_dst);
    gat_agg_l2<<<AGG_BLOCKS, 256, 0, stream>>>(row_start, csr, h2, a_src, a_dst, bias2, out);
}